// Round 9
// baseline (658.554 us; speedup 1.0000x reference)
//
#include <hip/hip_runtime.h>
#include <hip/hip_bf16.h>
#include <math.h>

#define B_ 8
#define C_ 64
#define H_ 128
#define W_ 128
#define HW_ (H_*W_)
#define HP_ 130
#define WP_ 130
#define XPLANE_ (HP_*WP_*64)     // padded NHWC plane per batch (halfwords)

typedef __attribute__((ext_vector_type(8))) short bf16x8;
typedef __attribute__((ext_vector_type(4))) float f32x4;
typedef __attribute__((ext_vector_type(4))) unsigned int u32x4;

// ---------------------------------------------------------------------------
// Zero only the 1-px halo ring of the 3 padded NHWC planes (blocks 0..23)
// and the wT3 pad region (block 24).
// ---------------------------------------------------------------------------
__global__ __launch_bounds__(256)
void zero_halo_k(unsigned int* __restrict__ planes, unsigned int* __restrict__ wT3u)
{
    const int blk = blockIdx.x;
    if (blk < 24){
        const int plane = blk >> 3, batch = blk & 7;
        unsigned int* base = planes + (size_t)plane*4326400 + (size_t)batch*(XPLANE_/2);
        for (int i = threadIdx.x; i < 516*32; i += 256){
            const int u = i & 31, p = i >> 5;
            int h, w;
            if (p < 130)      { h = 0;        w = p;       }
            else if (p < 260) { h = 129;      w = p - 130; }
            else if (p < 388) { h = p - 259;  w = 0;       }
            else              { h = p - 387;  w = 129;     }
            base[(size_t)(h*130 + w)*32 + u] = 0u;
        }
    } else {
        for (int i = threadIdx.x; i < 13824; i += 256) wT3u[i] = 0u;
    }
}

// ---------------------------------------------------------------------------
// x NCHW fp32 -> xTp padded NHWC bf16 (interior only; halo pre-zeroed).
// ---------------------------------------------------------------------------
__global__ __launch_bounds__(256)
void xpose_x_k(const float* __restrict__ x, __hip_bfloat16* __restrict__ xTp)
{
    __shared__ float tile[64][65];
    const int tid = threadIdx.x;
    const int w0 = blockIdx.x*64, h = blockIdx.y, b = blockIdx.z;
    const float* xb = x + (size_t)b*64*HW_;
    for (int i = tid; i < 4096; i += 256){
        const int c = i >> 6, px = i & 63;
        tile[c][px] = xb[(size_t)c*HW_ + h*W_ + w0 + px];
    }
    __syncthreads();
    __hip_bfloat16* ob = xTp + (size_t)b*XPLANE_;
    for (int i = tid; i < 512; i += 256){
        const int px = i >> 3, cs = i & 7;
        union { bf16x8 v; __hip_bfloat16 h8[8]; } R;
#pragma unroll
        for (int j=0;j<8;j++) R.h8[j] = __float2bfloat16(tile[cs*8+j][px]);
        *(bf16x8*)&ob[((size_t)(h+1)*WP_ + (w0+px+1))*64 + cs*8] = R.v;
    }
}

// ---------------------------------------------------------------------------
// All weight transposes+casts in one launch: w fp32 [O][64][9] -> bf16 [9][OPAD][64]
// ---------------------------------------------------------------------------
__device__ __forceinline__ void cast_one(const float* __restrict__ w,
                                         __hip_bfloat16* __restrict__ wT,
                                         int O, int OPAD, int idx)
{
    if (idx >= 9*O*64) return;
    const int k = idx / (O*64);
    const int rem = idx - k*O*64;
    const int o = rem >> 6, c = rem & 63;
    wT[((size_t)k*OPAD + o)*64 + c] = __float2bfloat16(w[((size_t)o*64 + c)*9 + k]);
}

__global__ __launch_bounds__(256)
void cast_all_k(const float* __restrict__ w1, const float* __restrict__ w2,
                const float* __restrict__ w3, const float* __restrict__ wa,
                const float* __restrict__ wd,
                __hip_bfloat16* __restrict__ wT1, __hip_bfloat16* __restrict__ wT2,
                __hip_bfloat16* __restrict__ wT3, __hip_bfloat16* __restrict__ wTa,
                __hip_bfloat16* __restrict__ wTd)
{
    const int bx = blockIdx.x, tid = threadIdx.x;
    if      (bx < 144) cast_one(w1, wT1,  64,  64, bx*256 + tid);
    else if (bx < 288) cast_one(w2, wT2,  64,  64, (bx-144)*256 + tid);
    else if (bx < 369) cast_one(w3, wT3,  36,  48, (bx-288)*256 + tid);
    else if (bx < 657) cast_one(wa, wTa, 128, 128, (bx-369)*256 + tid);
    else               cast_one(wd, wTd, 128, 128, (bx-657)*256 + tid);
}

// ---------------------------------------------------------------------------
// Implicit-GEMM 3x3 conv via MFMA (R4-proven: wA LDS tile, XOR swizzle).
// ---------------------------------------------------------------------------
enum OutMode { OUT_NHWC_PAD_RELU, OUT_NCHW_F32, OUT_NCHW_BF16 };

template<int G, int CO_TOT, OutMode MODE>
__global__ __launch_bounds__(256)
void conv_mfma_k(const __hip_bfloat16* __restrict__ xT,
                 const __hip_bfloat16* __restrict__ wT, int o_total,
                 void* __restrict__ outp)
{
    __shared__ __hip_bfloat16 wA[64][64];
    const int tid = threadIdx.x, lane = tid & 63, wid = tid >> 6;
    const int l15 = lane & 15, khi = lane >> 4;
    const int ow0 = blockIdx.x*64, oh = blockIdx.y;
    const int b = blockIdx.z & 7, cob = blockIdx.z >> 3;
    const int px = wid*16 + l15;
    const __hip_bfloat16* xb = xT + (size_t)b*XPLANE_;

    f32x4 acc[G];
    const f32x4 vz = {0.f,0.f,0.f,0.f};
#pragma unroll
    for (int g=0; g<G; ++g) acc[g] = vz;

    for (int k=0; k<9; ++k){
        const int dy = k/3 - 1, dxk = k%3 - 1;
        __syncthreads();
        for (int i=tid; i<G*16*8; i+=256){
            const int o = i >> 3, cs = i & 7;
            *(bf16x8*)&wA[o][((cs ^ (o&7))*8)] =
                *(const bf16x8*)&wT[((size_t)k*o_total + cob*64 + o)*64 + cs*8];
        }
        __syncthreads();
        const int base = (((oh+1+dy)*WP_) + (ow0+px+1+dxk))*64;
#pragma unroll
        for (int s=0; s<2; ++s){
            const bf16x8 bfr = *(const bf16x8*)&xb[base + s*32 + khi*8];
            const int c8 = ((s*4 + khi) ^ (l15 & 7))*8;
#pragma unroll
            for (int g=0; g<G; ++g){
                const bf16x8 afr = *(const bf16x8*)&wA[g*16 + l15][c8];
                acc[g] = __builtin_amdgcn_mfma_f32_16x16x32_bf16(afr, bfr, acc[g], 0,0,0);
            }
        }
    }
    // ---- epilogue ----
    if (MODE == OUT_NHWC_PAD_RELU){
        __hip_bfloat16* ob = (__hip_bfloat16*)outp + (size_t)b*XPLANE_;
        const size_t orow = ((size_t)(oh+1)*WP_ + (ow0+px+1))*64;
#pragma unroll
        for (int g=0; g<G; ++g){
            union { short4 s4; __hip_bfloat16 h[4]; } o4;
#pragma unroll
            for (int r=0;r<4;r++) o4.h[r] = __float2bfloat16(fmaxf(acc[g][r], 0.f));
            *(short4*)&ob[orow + g*16 + khi*4] = o4.s4;
        }
    } else if (MODE == OUT_NCHW_F32){
        float* ob = (float*)outp;
#pragma unroll
        for (int g=0; g<G; ++g)
#pragma unroll
            for (int r=0;r<4;r++){
                const int co = cob*64 + g*16 + khi*4 + r;
                if (co < CO_TOT)
                    ob[(((size_t)b*CO_TOT + co)*H_ + oh)*W_ + ow0 + px] = acc[g][r];
            }
    } else {
        __hip_bfloat16* ob = (__hip_bfloat16*)outp;
#pragma unroll
        for (int g=0; g<G; ++g)
#pragma unroll
            for (int r=0;r<4;r++){
                const int co = cob*64 + g*16 + khi*4 + r;
                ob[(((size_t)b*CO_TOT + co)*H_ + oh)*W_ + ow0 + px] = __float2bfloat16(acc[g][r]);
            }
    }
}

// ---------------------------------------------------------------------------
// 4-corner bilinear blend of 8 consecutive channels (NHWC bf16) -> bf16x8.
// ---------------------------------------------------------------------------
__device__ __forceinline__ bf16x8 blend4(const __hip_bfloat16* __restrict__ xb,
                                         int a00, int dxo, int dro, float4 w)
{
    const u32x4 q00 = *(const u32x4*)(xb + a00);
    const u32x4 q01 = *(const u32x4*)(xb + a00 + dxo);
    const u32x4 q10 = *(const u32x4*)(xb + a00 + dro);
    const u32x4 q11 = *(const u32x4*)(xb + a00 + dro + dxo);
    union { bf16x8 v; __hip_bfloat16 h[8]; } R;
#pragma unroll
    for (int p=0;p<4;++p){
        const float l00 = __uint_as_float(q00[p]<<16), h00 = __uint_as_float(q00[p]&0xFFFF0000u);
        const float l01 = __uint_as_float(q01[p]<<16), h01 = __uint_as_float(q01[p]&0xFFFF0000u);
        const float l10 = __uint_as_float(q10[p]<<16), h10 = __uint_as_float(q10[p]&0xFFFF0000u);
        const float l11 = __uint_as_float(q11[p]<<16), h11 = __uint_as_float(q11[p]&0xFFFF0000u);
        R.h[2*p  ] = __float2bfloat16(w.x*l00 + w.y*l01 + w.z*l10 + w.w*l11);
        R.h[2*p+1] = __float2bfloat16(w.x*h00 + w.y*h01 + w.z*h10 + w.w*h11);
    }
    return R.v;
}

// ---------------------------------------------------------------------------
struct Meta { int a00, dxo, dro; float4 w4; };

__device__ __forceinline__ Meta mkmeta(int oh, int ow0, int px, int k,
                                       float oy, float ox)
{
    const int kr = k/3, kc = k - 3*kr;
    const float py  = (float)(oh  - 1 + kr) + oy;
    const float pxx = (float)(ow0 + px - 1 + kc) + ox;
    const float y0f = floorf(py), x0f = floorf(pxx);
    const float ay = py - y0f, ax = pxx - x0f;
    const int y0 = (int)y0f, x0 = (int)x0f;
    const int y1 = y0 + 1,   x1 = x0 + 1;
    const float my0 = (y0 >= 0 && y0 < H_) ? 1.f : 0.f;
    const float my1 = (y1 >= 0 && y1 < H_) ? 1.f : 0.f;
    const float mx0 = (x0 >= 0 && x0 < W_) ? 1.f : 0.f;
    const float mx1 = (x1 >= 0 && x1 < W_) ? 1.f : 0.f;
    const int y0c = min(max(y0,0),H_-1), y1c = min(max(y1,0),H_-1);
    const int x0c = min(max(x0,0),W_-1), x1c = min(max(x1,0),W_-1);
    const float wy0 = my0*(1.f-ay), wy1 = my1*ay;
    const float wx0 = mx0*(1.f-ax), wx1 = mx1*ax;
    Meta m;
    m.a00 = ((y0c+1)*WP_ + (x0c+1))*64;
    m.dxo = (x1c-x0c)*64;
    m.dro = (y1c-y0c)*WP_*64;
    m.w4  = make_float4(wy0*wx0, wy0*wx1, wy1*wx0, wy1*wx1);
    return m;
}

// ---------------------------------------------------------------------------
// Fused deformable conv (MFMA) + softmax attention (R7 best, unchanged):
// tap-outer/dk-inner, double-buffered wA, async-split staging, 9 barriers.
// ---------------------------------------------------------------------------
__global__ __launch_bounds__(256)
void deform_att_k(const __hip_bfloat16* __restrict__ xT,
                  const float* __restrict__ off,
                  const __hip_bfloat16* __restrict__ att,
                  const __hip_bfloat16* __restrict__ wTd,   // [9][128][64]
                  float* __restrict__ out)
{
    __shared__ __hip_bfloat16 wA[2][2][64][64];   // [buf][dk][co][c]
    const int tid = threadIdx.x, lane = tid & 63, wid = tid >> 6;
    const int l15 = lane & 15, khi = lane >> 4;
    const int ow0 = blockIdx.x*64, oh = blockIdx.y, b = blockIdx.z;
    const int px = wid*16 + l15;
    const __hip_bfloat16* xb = xT + (size_t)b*XPLANE_;
    const float* offb = off + (size_t)b*36*HW_ + (size_t)oh*W_ + ow0 + px;
    const int srow = tid >> 3, scs = tid & 7;
    const int swz = (scs ^ (srow & 7)) * 8;

    f32x4 acc[2][4];
    const f32x4 vz = {0.f,0.f,0.f,0.f};
#pragma unroll
    for (int d=0; d<2; ++d)
#pragma unroll
        for (int g=0; g<4; ++g) acc[d][g] = vz;

    {
        const __hip_bfloat16* ws0 = &wTd[(size_t)srow*64 + scs*8];
        *(bf16x8*)&wA[0][0][srow   ][swz] = *(const bf16x8*)ws0;
        *(bf16x8*)&wA[0][0][srow+32][swz] = *(const bf16x8*)(ws0 + 32*64);
        *(bf16x8*)&wA[0][1][srow   ][swz] = *(const bf16x8*)(ws0 + 64*64);
        *(bf16x8*)&wA[0][1][srow+32][swz] = *(const bf16x8*)(ws0 + 96*64);
    }
    float oyr0 = offb[0],                 oxr0 = offb[HW_];
    float oyr1 = offb[(size_t)18*HW_],    oxr1 = offb[(size_t)19*HW_];
    __syncthreads();

    for (int k=0; k<9; ++k){
        bf16x8 nw00 = {}, nw01 = {}, nw10 = {}, nw11 = {};
        float noy0=0.f, nox0=0.f, noy1=0.f, nox1=0.f;
        const bool hn = (k < 8);
        if (hn){
            const __hip_bfloat16* ws0 = &wTd[((size_t)(k+1)*128 + srow)*64 + scs*8];
            nw00 = *(const bf16x8*)ws0;
            nw01 = *(const bf16x8*)(ws0 + 32*64);
            nw10 = *(const bf16x8*)(ws0 + 64*64);
            nw11 = *(const bf16x8*)(ws0 + 96*64);
            noy0 = offb[(size_t)(2*k+2)*HW_];
            nox0 = offb[(size_t)(2*k+3)*HW_];
            noy1 = offb[(size_t)(2*k+20)*HW_];
            nox1 = offb[(size_t)(2*k+21)*HW_];
        }
        const Meta m0 = mkmeta(oh, ow0, px, k, oyr0, oxr0);
        const Meta m1 = mkmeta(oh, ow0, px, k, oyr1, oxr1);
        const __hip_bfloat16 (*wr0)[64] = (const __hip_bfloat16 (*)[64])wA[k & 1][0];
        const __hip_bfloat16 (*wr1)[64] = (const __hip_bfloat16 (*)[64])wA[k & 1][1];
#pragma unroll
        for (int s=0; s<2; ++s){
            const bf16x8 b0 = blend4(xb, m0.a00 + s*32 + khi*8, m0.dxo, m0.dro, m0.w4);
            const bf16x8 b1 = blend4(xb, m1.a00 + s*32 + khi*8, m1.dxo, m1.dro, m1.w4);
            const int c8 = ((s*4 + khi) ^ (l15 & 7))*8;
#pragma unroll
            for (int g=0; g<4; ++g){
                const bf16x8 a0 = *(const bf16x8*)&wr0[g*16 + l15][c8];
                acc[0][g] = __builtin_amdgcn_mfma_f32_16x16x32_bf16(a0, b0, acc[0][g], 0,0,0);
            }
#pragma unroll
            for (int g=0; g<4; ++g){
                const bf16x8 a1 = *(const bf16x8*)&wr1[g*16 + l15][c8];
                acc[1][g] = __builtin_amdgcn_mfma_f32_16x16x32_bf16(a1, b1, acc[1][g], 0,0,0);
            }
        }
        if (hn){
            *(bf16x8*)&wA[(k+1)&1][0][srow   ][swz] = nw00;
            *(bf16x8*)&wA[(k+1)&1][0][srow+32][swz] = nw01;
            *(bf16x8*)&wA[(k+1)&1][1][srow   ][swz] = nw10;
            *(bf16x8*)&wA[(k+1)&1][1][srow+32][swz] = nw11;
            oyr0 = noy0; oxr0 = nox0; oyr1 = noy1; oxr1 = nox1;
        }
        __syncthreads();
    }
#pragma unroll
    for (int g=0; g<4; ++g)
#pragma unroll
        for (int r=0; r<4; ++r){
            const int co = g*16 + khi*4 + r;
            const float a0 = __bfloat162float(att[(((size_t)b*128      + co)*H_ + oh)*W_ + ow0 + px]);
            const float a1 = __bfloat162float(att[(((size_t)b*128 + 64 + co)*H_ + oh)*W_ + ow0 + px]);
            const float f0 = 1.f / (1.f + __expf(a1 - a0));
            out[(((size_t)b*64 + co)*H_ + oh)*W_ + ow0 + px] =
                acc[0][g][r]*f0 + acc[1][g][r]*(1.f - f0);
        }
}

// ===========================================================================
// ABLATION PROBES (write to scratch; diagnostic only)
// ===========================================================================

// V2: meta + raw corner gathers only (floor cost of the gather stream).
__global__ __launch_bounds__(256)
void abl_gather_k(const __hip_bfloat16* __restrict__ xT,
                  const float* __restrict__ off, float* __restrict__ scr)
{
    const int tid = threadIdx.x, lane = tid & 63, wid = tid >> 6;
    const int l15 = lane & 15, khi = lane >> 4;
    const int ow0 = blockIdx.x*64, oh = blockIdx.y, b = blockIdx.z;
    const int px = wid*16 + l15;
    const __hip_bfloat16* xb = xT + (size_t)b*XPLANE_;
    const float* offb = off + (size_t)b*36*HW_ + (size_t)oh*W_ + ow0 + px;
    float fsum = 0.f;
    for (int k=0; k<9; ++k){
#pragma unroll
        for (int dk=0; dk<2; ++dk){
            const float oy = offb[(size_t)(dk*18 + 2*k    )*HW_];
            const float ox = offb[(size_t)(dk*18 + 2*k + 1)*HW_];
            const Meta m = mkmeta(oh, ow0, px, k, oy, ox);
            fsum += m.w4.x + m.w4.w;      // keep mask-weight math alive
#pragma unroll
            for (int s=0; s<2; ++s){
                const __hip_bfloat16* p = xb + m.a00 + s*32 + khi*8;
                const u32x4 q00 = *(const u32x4*)p;
                const u32x4 q01 = *(const u32x4*)(p + m.dxo);
                const u32x4 q10 = *(const u32x4*)(p + m.dro);
                const u32x4 q11 = *(const u32x4*)(p + m.dro + m.dxo);
                asm volatile("" :: "v"(q00), "v"(q01), "v"(q10), "v"(q11));
                fsum += (float)q00[0];
            }
        }
    }
    const int gid = ((blockIdx.z*128 + blockIdx.y)*2 + blockIdx.x)*256 + tid;
    scr[gid] = fsum;
}

// V1: meta + gathers + blend (adds the bilinear-blend VALU cost).
__global__ __launch_bounds__(256)
void abl_blend_k(const __hip_bfloat16* __restrict__ xT,
                 const float* __restrict__ off, float* __restrict__ scr)
{
    const int tid = threadIdx.x, lane = tid & 63, wid = tid >> 6;
    const int l15 = lane & 15, khi = lane >> 4;
    const int ow0 = blockIdx.x*64, oh = blockIdx.y, b = blockIdx.z;
    const int px = wid*16 + l15;
    const __hip_bfloat16* xb = xT + (size_t)b*XPLANE_;
    const float* offb = off + (size_t)b*36*HW_ + (size_t)oh*W_ + ow0 + px;
    float fsum = 0.f;
    for (int k=0; k<9; ++k){
#pragma unroll
        for (int dk=0; dk<2; ++dk){
            const float oy = offb[(size_t)(dk*18 + 2*k    )*HW_];
            const float ox = offb[(size_t)(dk*18 + 2*k + 1)*HW_];
            const Meta m = mkmeta(oh, ow0, px, k, oy, ox);
#pragma unroll
            for (int s=0; s<2; ++s){
                const bf16x8 bfr = blend4(xb, m.a00 + s*32 + khi*8, m.dxo, m.dro, m.w4);
                asm volatile("" :: "v"(bfr));
                fsum += (float)bfr[0];
            }
        }
    }
    const int gid = ((blockIdx.z*128 + blockIdx.y)*2 + blockIdx.x)*256 + tid;
    scr[gid] = fsum;
}

// V3: byte-identical structure to deform_att_k (same staging/barriers/MFMA/
// epilogue/regs) but gather base clamped into a 21KB L1-resident window.
// V3 vs real isolates the SCATTEREDNESS penalty at identical regime.
__global__ __launch_bounds__(256)
void abl_l1hot_k(const __hip_bfloat16* __restrict__ xT,
                 const float* __restrict__ off,
                 const __hip_bfloat16* __restrict__ att,
                 const __hip_bfloat16* __restrict__ wTd,
                 float* __restrict__ scr)
{
    __shared__ __hip_bfloat16 wA[2][2][64][64];
    const int tid = threadIdx.x, lane = tid & 63, wid = tid >> 6;
    const int l15 = lane & 15, khi = lane >> 4;
    const int ow0 = blockIdx.x*64, oh = blockIdx.y, b = blockIdx.z;
    const int px = wid*16 + l15;
    const __hip_bfloat16* xb = xT + (size_t)b*XPLANE_;
    const float* offb = off + (size_t)b*36*HW_ + (size_t)oh*W_ + ow0 + px;
    const int srow = tid >> 3, scs = tid & 7;
    const int swz = (scs ^ (srow & 7)) * 8;

    f32x4 acc[2][4];
    const f32x4 vz = {0.f,0.f,0.f,0.f};
#pragma unroll
    for (int d=0; d<2; ++d)
#pragma unroll
        for (int g=0; g<4; ++g) acc[d][g] = vz;

    {
        const __hip_bfloat16* ws0 = &wTd[(size_t)srow*64 + scs*8];
        *(bf16x8*)&wA[0][0][srow   ][swz] = *(const bf16x8*)ws0;
        *(bf16x8*)&wA[0][0][srow+32][swz] = *(const bf16x8*)(ws0 + 32*64);
        *(bf16x8*)&wA[0][1][srow   ][swz] = *(const bf16x8*)(ws0 + 64*64);
        *(bf16x8*)&wA[0][1][srow+32][swz] = *(const bf16x8*)(ws0 + 96*64);
    }
    float oyr0 = offb[0],                 oxr0 = offb[HW_];
    float oyr1 = offb[(size_t)18*HW_],    oxr1 = offb[(size_t)19*HW_];
    __syncthreads();

    for (int k=0; k<9; ++k){
        bf16x8 nw00 = {}, nw01 = {}, nw10 = {}, nw11 = {};
        float noy0=0.f, nox0=0.f, noy1=0.f, nox1=0.f;
        const bool hn = (k < 8);
        if (hn){
            const __hip_bfloat16* ws0 = &wTd[((size_t)(k+1)*128 + srow)*64 + scs*8];
            nw00 = *(const bf16x8*)ws0;
            nw01 = *(const bf16x8*)(ws0 + 32*64);
            nw10 = *(const bf16x8*)(ws0 + 64*64);
            nw11 = *(const bf16x8*)(ws0 + 96*64);
            noy0 = offb[(size_t)(2*k+2)*HW_];
            nox0 = offb[(size_t)(2*k+3)*HW_];
            noy1 = offb[(size_t)(2*k+20)*HW_];
            nox1 = offb[(size_t)(2*k+21)*HW_];
        }
        Meta m0 = mkmeta(oh, ow0, px, k, oyr0, oxr0);
        Meta m1 = mkmeta(oh, ow0, px, k, oyr1, oxr1);
        m0.a00 &= 2047;   // <-- ONLY change vs real: L1-resident window
        m1.a00 &= 2047;
        const __hip_bfloat16 (*wr0)[64] = (const __hip_bfloat16 (*)[64])wA[k & 1][0];
        const __hip_bfloat16 (*wr1)[64] = (const __hip_bfloat16 (*)[64])wA[k & 1][1];
#pragma unroll
        for (int s=0; s<2; ++s){
            const bf16x8 b0 = blend4(xb, m0.a00 + s*32 + khi*8, m0.dxo, m0.dro, m0.w4);
            const bf16x8 b1 = blend4(xb, m1.a00 + s*32 + khi*8, m1.dxo, m1.dro, m1.w4);
            const int c8 = ((s*4 + khi) ^ (l15 & 7))*8;
#pragma unroll
            for (int g=0; g<4; ++g){
                const bf16x8 a0 = *(const bf16x8*)&wr0[g*16 + l15][c8];
                acc[0][g] = __builtin_amdgcn_mfma_f32_16x16x32_bf16(a0, b0, acc[0][g], 0,0,0);
            }
#pragma unroll
            for (int g=0; g<4; ++g){
                const bf16x8 a1 = *(const bf16x8*)&wr1[g*16 + l15][c8];
                acc[1][g] = __builtin_amdgcn_mfma_f32_16x16x32_bf16(a1, b1, acc[1][g], 0,0,0);
            }
        }
        if (hn){
            *(bf16x8*)&wA[(k+1)&1][0][srow   ][swz] = nw00;
            *(bf16x8*)&wA[(k+1)&1][0][srow+32][swz] = nw01;
            *(bf16x8*)&wA[(k+1)&1][1][srow   ][swz] = nw10;
            *(bf16x8*)&wA[(k+1)&1][1][srow+32][swz] = nw11;
            oyr0 = noy0; oxr0 = nox0; oyr1 = noy1; oxr1 = nox1;
        }
        __syncthreads();
    }
    float red = 0.f;
#pragma unroll
    for (int g=0; g<4; ++g)
#pragma unroll
        for (int r=0; r<4; ++r){
            const int co = g*16 + khi*4 + r;
            const float a0 = __bfloat162float(att[(((size_t)b*128      + co)*H_ + oh)*W_ + ow0 + px]);
            const float a1 = __bfloat162float(att[(((size_t)b*128 + 64 + co)*H_ + oh)*W_ + ow0 + px]);
            const float f0 = 1.f / (1.f + __expf(a1 - a0));
            red += acc[0][g][r]*f0 + acc[1][g][r]*(1.f - f0);
        }
    const int gid = ((blockIdx.z*128 + blockIdx.y)*2 + blockIdx.x)*256 + tid;
    scr[gid] = red;
}

// ---------------------------------------------------------------------------
extern "C" void kernel_launch(void* const* d_in, const int* in_sizes, int n_in,
                              void* d_out, int out_size, void* d_ws, size_t ws_size,
                              hipStream_t stream)
{
    const float* x  = (const float*)d_in[0];
    const float* w1 = (const float*)d_in[1];
    const float* w2 = (const float*)d_in[2];
    const float* w3 = (const float*)d_in[3];
    const float* wa = (const float*)d_in[4];
    const float* wd = (const float*)d_in[5];
    float* out = (float*)d_out;

    // ---- workspace layout (halfword units for bf16 regions) ----
    __hip_bfloat16* xTp  = (__hip_bfloat16*)d_ws;       // 8,652,800
    __hip_bfloat16* m1Tp = xTp  + (size_t)8652800;      // 8,652,800
    __hip_bfloat16* m2Tp = m1Tp + (size_t)8652800;      // 8,652,800
    __hip_bfloat16* wT1  = m2Tp + (size_t)8652800;      // 36864
    __hip_bfloat16* wT2  = wT1  + 36864;                // 36864
    __hip_bfloat16* wT3  = wT2  + 36864;                // 27648
    __hip_bfloat16* wTa  = wT3  + 27648;                // 73728
    __hip_bfloat16* wTd  = wTa  + 73728;                // 73728
    float*          offs = (float*)(wTd + 73728);       // 4,718,592 fp32
    float*          scr  = offs + 4718592;              // 524,288 fp32 (ablation)
    __hip_bfloat16* att16 = m1Tp;   // aliases m1Tp+m2Tp (both dead by then)

    const dim3 blk(256);
    zero_halo_k<<<dim3(25), blk, 0, stream>>>((unsigned int*)xTp, (unsigned int*)wT3);
    xpose_x_k<<<dim3(2,128,8), blk, 0, stream>>>(x, xTp);
    cast_all_k<<<dim3(945), blk, 0, stream>>>(w1,w2,w3,wa,wd, wT1,wT2,wT3,wTa,wTd);
    conv_mfma_k<4,  64, OUT_NHWC_PAD_RELU><<<dim3(2,128,8),  blk, 0, stream>>>(xTp,  wT1,  64, m1Tp);
    conv_mfma_k<4,  64, OUT_NHWC_PAD_RELU><<<dim3(2,128,8),  blk, 0, stream>>>(m1Tp, wT2,  64, m2Tp);
    conv_mfma_k<3,  36, OUT_NCHW_F32     ><<<dim3(2,128,8),  blk, 0, stream>>>(m2Tp, wT3,  48, offs);
    conv_mfma_k<4, 128, OUT_NCHW_BF16    ><<<dim3(2,128,16), blk, 0, stream>>>(xTp,  wTa, 128, att16);
    deform_att_k<<<dim3(2,128,8), blk, 0, stream>>>(xTp, offs, att16, wTd, out);
    // ---- ablation probes (diagnostic; write scratch only) ----
    abl_gather_k<<<dim3(2,128,8), blk, 0, stream>>>(xTp, offs, scr);
    abl_blend_k <<<dim3(2,128,8), blk, 0, stream>>>(xTp, offs, scr);
    abl_l1hot_k <<<dim3(2,128,8), blk, 0, stream>>>(xTp, offs, att16, wTd, scr);
}

// Round 10
// 321.288 us; speedup vs baseline: 2.0497x; 2.0497x over previous
//
#include <hip/hip_runtime.h>
#include <hip/hip_bf16.h>
#include <math.h>

#define B_ 8
#define C_ 64
#define H_ 128
#define W_ 128
#define HW_ (H_*W_)
#define HP_ 130
#define WP_ 130
#define XPLANE_ (HP_*WP_*64)     // padded NHWC plane per batch (halfwords)

typedef __attribute__((ext_vector_type(8))) short bf16x8;
typedef __attribute__((ext_vector_type(4))) float f32x4;
typedef __attribute__((ext_vector_type(4))) unsigned int u32x4;

// ---------------------------------------------------------------------------
// async global->LDS 16B/lane: per-lane GLOBAL address, wave-uniform LDS base
// (HW adds lane*16 to the LDS side itself).
// ---------------------------------------------------------------------------
__device__ __forceinline__ void gload16(const void* g, void* l)
{
    __builtin_amdgcn_global_load_lds(
        (const __attribute__((address_space(1))) void*)g,
        (__attribute__((address_space(3))) void*)l, 16, 0, 0);
}

// ---------------------------------------------------------------------------
// Zero the output (atomic accumulation target) -- 8,388,608 floats.
// ---------------------------------------------------------------------------
__global__ __launch_bounds__(256)
void zero_out_k(u32x4* __restrict__ p)
{
    const int n = 8388608/4;
    const u32x4 z = {0u,0u,0u,0u};
    for (int i = blockIdx.x*256 + threadIdx.x; i < n; i += gridDim.x*256)
        p[i] = z;
}

// ---------------------------------------------------------------------------
// Zero only the 1-px halo ring of the 3 padded NHWC planes (blocks 0..23)
// and the wT3 pad region (block 24).
// ---------------------------------------------------------------------------
__global__ __launch_bounds__(256)
void zero_halo_k(unsigned int* __restrict__ planes, unsigned int* __restrict__ wT3u)
{
    const int blk = blockIdx.x;
    if (blk < 24){
        const int plane = blk >> 3, batch = blk & 7;
        unsigned int* base = planes + (size_t)plane*4326400 + (size_t)batch*(XPLANE_/2);
        for (int i = threadIdx.x; i < 516*32; i += 256){
            const int u = i & 31, p = i >> 5;
            int h, w;
            if (p < 130)      { h = 0;        w = p;       }
            else if (p < 260) { h = 129;      w = p - 130; }
            else if (p < 388) { h = p - 259;  w = 0;       }
            else              { h = p - 387;  w = 129;     }
            base[(size_t)(h*130 + w)*32 + u] = 0u;
        }
    } else {
        for (int i = threadIdx.x; i < 13824; i += 256) wT3u[i] = 0u;
    }
}

// ---------------------------------------------------------------------------
// x NCHW fp32 -> xTp padded NHWC bf16 (interior only; halo pre-zeroed).
// ---------------------------------------------------------------------------
__global__ __launch_bounds__(256)
void xpose_x_k(const float* __restrict__ x, __hip_bfloat16* __restrict__ xTp)
{
    __shared__ float tile[64][65];
    const int tid = threadIdx.x;
    const int w0 = blockIdx.x*64, h = blockIdx.y, b = blockIdx.z;
    const float* xb = x + (size_t)b*64*HW_;
    for (int i = tid; i < 4096; i += 256){
        const int c = i >> 6, px = i & 63;
        tile[c][px] = xb[(size_t)c*HW_ + h*W_ + w0 + px];
    }
    __syncthreads();
    __hip_bfloat16* ob = xTp + (size_t)b*XPLANE_;
    for (int i = tid; i < 512; i += 256){
        const int px = i >> 3, cs = i & 7;
        union { bf16x8 v; __hip_bfloat16 h8[8]; } R;
#pragma unroll
        for (int j=0;j<8;j++) R.h8[j] = __float2bfloat16(tile[cs*8+j][px]);
        *(bf16x8*)&ob[((size_t)(h+1)*WP_ + (w0+px+1))*64 + cs*8] = R.v;
    }
}

// ---------------------------------------------------------------------------
// Weight transforms (one launch):
//  - convs: w fp32 [O][64][9] -> wT bf16 [9][OPAD][64]  (R4 layout)
//  - deform: wd fp32 [dk][o][c][k] -> wTdS bf16, PRE-SWIZZLED so that a
//    linear global_load_lds DMA leaves LDS holding the XOR-swizzled tile:
//    wTdS[(k*2+dk)*4096 + o*64 + c8*8+j] = wd[dk][o][(c8^(o&7))*8+j][k]
// ---------------------------------------------------------------------------
__device__ __forceinline__ void cast_one(const float* __restrict__ w,
                                         __hip_bfloat16* __restrict__ wT,
                                         int O, int OPAD, int idx)
{
    if (idx >= 9*O*64) return;
    const int k = idx / (O*64);
    const int rem = idx - k*O*64;
    const int o = rem >> 6, c = rem & 63;
    wT[((size_t)k*OPAD + o)*64 + c] = __float2bfloat16(w[((size_t)o*64 + c)*9 + k]);
}

__device__ __forceinline__ void pack_wdS(const float* __restrict__ wd,
                                         __hip_bfloat16* __restrict__ wTdS, int idx)
{
    if (idx >= 73728) return;
    const int col = idx & 63;
    const int o   = (idx >> 6) & 63;
    const int t   = idx >> 12;          // k*2+dk
    const int k = t >> 1, dk = t & 1;
    const int c8 = col >> 3, j = col & 7;
    const int c  = ((c8 ^ (o & 7)) << 3) + j;
    wTdS[idx] = __float2bfloat16(wd[(((size_t)(dk*64 + o))*64 + c)*9 + k]);
}

__global__ __launch_bounds__(256)
void cast_all_k(const float* __restrict__ w1, const float* __restrict__ w2,
                const float* __restrict__ w3, const float* __restrict__ wa,
                const float* __restrict__ wd,
                __hip_bfloat16* __restrict__ wT1, __hip_bfloat16* __restrict__ wT2,
                __hip_bfloat16* __restrict__ wT3, __hip_bfloat16* __restrict__ wTa,
                __hip_bfloat16* __restrict__ wTdS)
{
    const int bx = blockIdx.x, tid = threadIdx.x;
    if      (bx < 144) cast_one(w1, wT1,  64,  64, bx*256 + tid);
    else if (bx < 288) cast_one(w2, wT2,  64,  64, (bx-144)*256 + tid);
    else if (bx < 369) cast_one(w3, wT3,  36,  48, (bx-288)*256 + tid);
    else if (bx < 657) cast_one(wa, wTa, 128, 128, (bx-369)*256 + tid);
    else               pack_wdS(wd, wTdS, (bx-657)*256 + tid);
}

// ---------------------------------------------------------------------------
// Implicit-GEMM 3x3 conv via MFMA (R4-proven: wA LDS tile, XOR swizzle).
// ---------------------------------------------------------------------------
enum OutMode { OUT_NHWC_PAD_RELU, OUT_NCHW_F32, OUT_NCHW_BF16 };

template<int G, int CO_TOT, OutMode MODE>
__global__ __launch_bounds__(256)
void conv_mfma_k(const __hip_bfloat16* __restrict__ xT,
                 const __hip_bfloat16* __restrict__ wT, int o_total,
                 void* __restrict__ outp)
{
    __shared__ __hip_bfloat16 wA[64][64];
    const int tid = threadIdx.x, lane = tid & 63, wid = tid >> 6;
    const int l15 = lane & 15, khi = lane >> 4;
    const int ow0 = blockIdx.x*64, oh = blockIdx.y;
    const int b = blockIdx.z & 7, cob = blockIdx.z >> 3;
    const int px = wid*16 + l15;
    const __hip_bfloat16* xb = xT + (size_t)b*XPLANE_;

    f32x4 acc[G];
    const f32x4 vz = {0.f,0.f,0.f,0.f};
#pragma unroll
    for (int g=0; g<G; ++g) acc[g] = vz;

    for (int k=0; k<9; ++k){
        const int dy = k/3 - 1, dxk = k%3 - 1;
        __syncthreads();
        for (int i=tid; i<G*16*8; i+=256){
            const int o = i >> 3, cs = i & 7;
            *(bf16x8*)&wA[o][((cs ^ (o&7))*8)] =
                *(const bf16x8*)&wT[((size_t)k*o_total + cob*64 + o)*64 + cs*8];
        }
        __syncthreads();
        const int base = (((oh+1+dy)*WP_) + (ow0+px+1+dxk))*64;
#pragma unroll
        for (int s=0; s<2; ++s){
            const bf16x8 bfr = *(const bf16x8*)&xb[base + s*32 + khi*8];
            const int c8 = ((s*4 + khi) ^ (l15 & 7))*8;
#pragma unroll
            for (int g=0; g<G; ++g){
                const bf16x8 afr = *(const bf16x8*)&wA[g*16 + l15][c8];
                acc[g] = __builtin_amdgcn_mfma_f32_16x16x32_bf16(afr, bfr, acc[g], 0,0,0);
            }
        }
    }
    // ---- epilogue ----
    if (MODE == OUT_NHWC_PAD_RELU){
        __hip_bfloat16* ob = (__hip_bfloat16*)outp + (size_t)b*XPLANE_;
        const size_t orow = ((size_t)(oh+1)*WP_ + (ow0+px+1))*64;
#pragma unroll
        for (int g=0; g<G; ++g){
            union { short4 s4; __hip_bfloat16 h[4]; } o4;
#pragma unroll
            for (int r=0;r<4;r++) o4.h[r] = __float2bfloat16(fmaxf(acc[g][r], 0.f));
            *(short4*)&ob[orow + g*16 + khi*4] = o4.s4;
        }
    } else if (MODE == OUT_NCHW_F32){
        float* ob = (float*)outp;
#pragma unroll
        for (int g=0; g<G; ++g)
#pragma unroll
            for (int r=0;r<4;r++){
                const int co = cob*64 + g*16 + khi*4 + r;
                if (co < CO_TOT)
                    ob[(((size_t)b*CO_TOT + co)*H_ + oh)*W_ + ow0 + px] = acc[g][r];
            }
    } else {
        __hip_bfloat16* ob = (__hip_bfloat16*)outp;
#pragma unroll
        for (int g=0; g<G; ++g)
#pragma unroll
            for (int r=0;r<4;r++){
                const int co = cob*64 + g*16 + khi*4 + r;
                ob[(((size_t)b*CO_TOT + co)*H_ + oh)*W_ + ow0 + px] = __float2bfloat16(acc[g][r]);
            }
    }
}

// ---------------------------------------------------------------------------
// 4-corner bilinear blend of 8 consecutive channels (NHWC bf16) -> bf16x8.
// ---------------------------------------------------------------------------
__device__ __forceinline__ bf16x8 blend4(const __hip_bfloat16* __restrict__ xb,
                                         int a00, int dxo, int dro, float4 w)
{
    const u32x4 q00 = *(const u32x4*)(xb + a00);
    const u32x4 q01 = *(const u32x4*)(xb + a00 + dxo);
    const u32x4 q10 = *(const u32x4*)(xb + a00 + dro);
    const u32x4 q11 = *(const u32x4*)(xb + a00 + dro + dxo);
    union { bf16x8 v; __hip_bfloat16 h[8]; } R;
#pragma unroll
    for (int p=0;p<4;++p){
        const float l00 = __uint_as_float(q00[p]<<16), h00 = __uint_as_float(q00[p]&0xFFFF0000u);
        const float l01 = __uint_as_float(q01[p]<<16), h01 = __uint_as_float(q01[p]&0xFFFF0000u);
        const float l10 = __uint_as_float(q10[p]<<16), h10 = __uint_as_float(q10[p]&0xFFFF0000u);
        const float l11 = __uint_as_float(q11[p]<<16), h11 = __uint_as_float(q11[p]&0xFFFF0000u);
        R.h[2*p  ] = __float2bfloat16(w.x*l00 + w.y*l01 + w.z*l10 + w.w*l11);
        R.h[2*p+1] = __float2bfloat16(w.x*h00 + w.y*h01 + w.z*h10 + w.w*h11);
    }
    return R.v;
}

// ---------------------------------------------------------------------------
struct Meta { int a00, dxo, dro; float4 w4; };

__device__ __forceinline__ Meta mkmeta(int oh, int ow0, int px, int k,
                                       float oy, float ox)
{
    const int kr = k/3, kc = k - 3*kr;
    const float py  = (float)(oh  - 1 + kr) + oy;
    const float pxx = (float)(ow0 + px - 1 + kc) + ox;
    const float y0f = floorf(py), x0f = floorf(pxx);
    const float ay = py - y0f, ax = pxx - x0f;
    const int y0 = (int)y0f, x0 = (int)x0f;
    const int y1 = y0 + 1,   x1 = x0 + 1;
    const float my0 = (y0 >= 0 && y0 < H_) ? 1.f : 0.f;
    const float my1 = (y1 >= 0 && y1 < H_) ? 1.f : 0.f;
    const float mx0 = (x0 >= 0 && x0 < W_) ? 1.f : 0.f;
    const float mx1 = (x1 >= 0 && x1 < W_) ? 1.f : 0.f;
    const int y0c = min(max(y0,0),H_-1), y1c = min(max(y1,0),H_-1);
    const int x0c = min(max(x0,0),W_-1), x1c = min(max(x1,0),W_-1);
    const float wy0 = my0*(1.f-ay), wy1 = my1*ay;
    const float wx0 = mx0*(1.f-ax), wx1 = mx1*ax;
    Meta m;
    m.a00 = ((y0c+1)*WP_ + (x0c+1))*64;
    m.dxo = (x1c-x0c)*64;
    m.dro = (y1c-y0c)*WP_*64;
    m.w4  = make_float4(wy0*wx0, wy0*wx1, wy1*wx0, wy1*wx1);
    return m;
}

// ---------------------------------------------------------------------------
// Fused deformable conv (MFMA) + softmax attention, v6:
//  - ONE dk per block (grid z = b*2+dk, 4096 blocks): acc 16 VGPR, LDS 21KB
//  - weights: async global_load_lds DMA from pre-swizzled wTdS (no ds_write,
//    no prefetch registers); double-buffered; 1 barrier/tap
//  - all 18 offset rows staged to LDS once (no per-tap strided off loads)
//  - epilogue: atomicAdd(out, feat*softmax_weight) into pre-zeroed out
// ---------------------------------------------------------------------------
__global__ __launch_bounds__(256)
void deform_att_k(const __hip_bfloat16* __restrict__ xT,
                  const float* __restrict__ off,
                  const __hip_bfloat16* __restrict__ att,
                  const __hip_bfloat16* __restrict__ wTdS,  // [k*2+dk][64][64] pre-swz
                  float* __restrict__ out)
{
    __shared__ __hip_bfloat16 wA[2][64][64];   // 16 KB double buffer
    __shared__ float offL[18][64];             // 4.5 KB
    const int tid = threadIdx.x, lane = tid & 63, wid = tid >> 6;
    const int l15 = lane & 15, khi = lane >> 4;
    const int ow0 = blockIdx.x*64, oh = blockIdx.y;
    const int b = blockIdx.z >> 1, dk = blockIdx.z & 1;
    const int px = wid*16 + l15;
    const __hip_bfloat16* xb = xT + (size_t)b*XPLANE_;

    // ---- stage this dk's 18 offset rows (coalesced) ----
    const float* offsrc = off + ((size_t)b*36 + dk*18)*HW_ + (size_t)oh*W_ + ow0;
    for (int i=tid; i<1152; i+=256){
        const int ch = i >> 6, p = i & 63;
        offL[ch][p] = offsrc[(size_t)ch*HW_ + p];
    }
    // ---- issue tap-0 weight DMA (8 x 1KB chunks; 2 per wave) ----
    {
        const __hip_bfloat16* gsrc = wTdS + (size_t)dk*4096;
#pragma unroll
        for (int i=0; i<2; ++i){
            const int ch = wid*2 + i;
            gload16(gsrc + ch*512 + lane*8, &wA[0][0][0] + ch*512);
        }
    }
    f32x4 acc[4];
    const f32x4 vz = {0.f,0.f,0.f,0.f};
#pragma unroll
    for (int g=0; g<4; ++g) acc[g] = vz;
    __syncthreads();   // drains DMA (vmcnt) + offL visible

    for (int k=0; k<9; ++k){
        // ---- issue next tap's weight DMA into the other buffer ----
        if (k < 8){
            const __hip_bfloat16* gsrc = wTdS + (size_t)((k+1)*2 + dk)*4096;
#pragma unroll
            for (int i=0; i<2; ++i){
                const int ch = wid*2 + i;
                gload16(gsrc + ch*512 + lane*8, &wA[(k+1)&1][0][0] + ch*512);
            }
        }
        // ---- meta from LDS offsets ----
        const float oy = offL[2*k  ][px];
        const float ox = offL[2*k+1][px];
        const Meta m = mkmeta(oh, ow0, px, k, oy, ox);
        const __hip_bfloat16 (*wr)[64] = (const __hip_bfloat16 (*)[64])wA[k & 1];
#pragma unroll
        for (int s=0; s<2; ++s){
            const bf16x8 bfr = blend4(xb, m.a00 + s*32 + khi*8, m.dxo, m.dro, m.w4);
            const int c8 = ((s*4 + khi) ^ (l15 & 7))*8;
#pragma unroll
            for (int g=0; g<4; ++g){
                const bf16x8 afr = *(const bf16x8*)&wr[g*16 + l15][c8];
                acc[g] = __builtin_amdgcn_mfma_f32_16x16x32_bf16(afr, bfr, acc[g], 0,0,0);
            }
        }
        __syncthreads();   // next-tap DMA drained; wA[k&1] reads done
    }
    // ---- epilogue: softmax weight + atomic accumulate ----
#pragma unroll
    for (int g=0; g<4; ++g)
#pragma unroll
        for (int r=0; r<4; ++r){
            const int co = g*16 + khi*4 + r;
            const float as = __bfloat162float(att[(((size_t)b*128 +    dk *64 + co)*H_ + oh)*W_ + ow0 + px]);
            const float ao = __bfloat162float(att[(((size_t)b*128 + (1-dk)*64 + co)*H_ + oh)*W_ + ow0 + px]);
            const float f = 1.f / (1.f + __expf(ao - as));
            atomicAdd(&out[(((size_t)b*64 + co)*H_ + oh)*W_ + ow0 + px], acc[g][r]*f);
        }
}

// ---------------------------------------------------------------------------
extern "C" void kernel_launch(void* const* d_in, const int* in_sizes, int n_in,
                              void* d_out, int out_size, void* d_ws, size_t ws_size,
                              hipStream_t stream)
{
    const float* x  = (const float*)d_in[0];
    const float* w1 = (const float*)d_in[1];
    const float* w2 = (const float*)d_in[2];
    const float* w3 = (const float*)d_in[3];
    const float* wa = (const float*)d_in[4];
    const float* wd = (const float*)d_in[5];
    float* out = (float*)d_out;

    // ---- workspace layout (halfword units for bf16 regions) ----
    __hip_bfloat16* xTp  = (__hip_bfloat16*)d_ws;       // 8,652,800
    __hip_bfloat16* m1Tp = xTp  + (size_t)8652800;      // 8,652,800
    __hip_bfloat16* m2Tp = m1Tp + (size_t)8652800;      // 8,652,800
    __hip_bfloat16* wT1  = m2Tp + (size_t)8652800;      // 36864
    __hip_bfloat16* wT2  = wT1  + 36864;                // 36864
    __hip_bfloat16* wT3  = wT2  + 36864;                // 27648
    __hip_bfloat16* wTa  = wT3  + 27648;                // 73728
    __hip_bfloat16* wTdS = wTa  + 73728;                // 73728 (pre-swizzled)
    float*          offs = (float*)(wTdS + 73728);      // 4,718,592 fp32
    __hip_bfloat16* att16 = m1Tp;   // aliases m1Tp+m2Tp (both dead by then)

    const dim3 blk(256);
    zero_out_k<<<dim3(1024), blk, 0, stream>>>((u32x4*)out);
    zero_halo_k<<<dim3(25), blk, 0, stream>>>((unsigned int*)xTp, (unsigned int*)wT3);
    xpose_x_k<<<dim3(2,128,8), blk, 0, stream>>>(x, xTp);
    cast_all_k<<<dim3(945), blk, 0, stream>>>(w1,w2,w3,wa,wd, wT1,wT2,wT3,wTa,wTdS);
    conv_mfma_k<4,  64, OUT_NHWC_PAD_RELU><<<dim3(2,128,8),  blk, 0, stream>>>(xTp,  wT1,  64, m1Tp);
    conv_mfma_k<4,  64, OUT_NHWC_PAD_RELU><<<dim3(2,128,8),  blk, 0, stream>>>(m1Tp, wT2,  64, m2Tp);
    conv_mfma_k<3,  36, OUT_NCHW_F32     ><<<dim3(2,128,8),  blk, 0, stream>>>(m2Tp, wT3,  48, offs);
    conv_mfma_k<4, 128, OUT_NCHW_BF16    ><<<dim3(2,128,16), blk, 0, stream>>>(xTp,  wTa, 128, att16);
    // fused deformable conv + attention (v6: dk-split, DMA weights, atomics)
    deform_att_k<<<dim3(2,128,16), blk, 0, stream>>>(xTp, offs, att16, wTdS, out);
}

// Round 11
// 281.205 us; speedup vs baseline: 2.3419x; 1.1425x over previous
//
#include <hip/hip_runtime.h>
#include <hip/hip_bf16.h>
#include <math.h>

#define B_ 8
#define C_ 64
#define H_ 128
#define W_ 128
#define HW_ (H_*W_)
#define HP_ 130
#define WP_ 130
#define XPLANE_ (HP_*WP_*64)     // padded NHWC plane per batch (halfwords)

typedef __attribute__((ext_vector_type(8))) short bf16x8;
typedef __attribute__((ext_vector_type(4))) float f32x4;
typedef __attribute__((ext_vector_type(4))) unsigned int u32x4;

// ---------------------------------------------------------------------------
// Zero only the 1-px halo ring of the 3 padded NHWC planes (blocks 0..23)
// and the wT3 pad region (block 24).
// ---------------------------------------------------------------------------
__global__ __launch_bounds__(256)
void zero_halo_k(unsigned int* __restrict__ planes, unsigned int* __restrict__ wT3u)
{
    const int blk = blockIdx.x;
    if (blk < 24){
        const int plane = blk >> 3, batch = blk & 7;
        unsigned int* base = planes + (size_t)plane*4326400 + (size_t)batch*(XPLANE_/2);
        for (int i = threadIdx.x; i < 516*32; i += 256){
            const int u = i & 31, p = i >> 5;
            int h, w;
            if (p < 130)      { h = 0;        w = p;       }
            else if (p < 260) { h = 129;      w = p - 130; }
            else if (p < 388) { h = p - 259;  w = 0;       }
            else              { h = p - 387;  w = 129;     }
            base[(size_t)(h*130 + w)*32 + u] = 0u;
        }
    } else {
        for (int i = threadIdx.x; i < 13824; i += 256) wT3u[i] = 0u;
    }
}

// ---------------------------------------------------------------------------
// x NCHW fp32 -> xTp padded NHWC bf16 (interior only; halo pre-zeroed).
// ---------------------------------------------------------------------------
__global__ __launch_bounds__(256)
void xpose_x_k(const float* __restrict__ x, __hip_bfloat16* __restrict__ xTp)
{
    __shared__ float tile[64][65];
    const int tid = threadIdx.x;
    const int w0 = blockIdx.x*64, h = blockIdx.y, b = blockIdx.z;
    const float* xb = x + (size_t)b*64*HW_;
    for (int i = tid; i < 4096; i += 256){
        const int c = i >> 6, px = i & 63;
        tile[c][px] = xb[(size_t)c*HW_ + h*W_ + w0 + px];
    }
    __syncthreads();
    __hip_bfloat16* ob = xTp + (size_t)b*XPLANE_;
    for (int i = tid; i < 512; i += 256){
        const int px = i >> 3, cs = i & 7;
        union { bf16x8 v; __hip_bfloat16 h8[8]; } R;
#pragma unroll
        for (int j=0;j<8;j++) R.h8[j] = __float2bfloat16(tile[cs*8+j][px]);
        *(bf16x8*)&ob[((size_t)(h+1)*WP_ + (w0+px+1))*64 + cs*8] = R.v;
    }
}

// ---------------------------------------------------------------------------
// All weight transposes+casts in one launch: w fp32 [O][64][9] -> bf16 [9][OPAD][64]
// ---------------------------------------------------------------------------
__device__ __forceinline__ void cast_one(const float* __restrict__ w,
                                         __hip_bfloat16* __restrict__ wT,
                                         int O, int OPAD, int idx)
{
    if (idx >= 9*O*64) return;
    const int k = idx / (O*64);
    const int rem = idx - k*O*64;
    const int o = rem >> 6, c = rem & 63;
    wT[((size_t)k*OPAD + o)*64 + c] = __float2bfloat16(w[((size_t)o*64 + c)*9 + k]);
}

__global__ __launch_bounds__(256)
void cast_all_k(const float* __restrict__ w1, const float* __restrict__ w2,
                const float* __restrict__ w3, const float* __restrict__ wa,
                const float* __restrict__ wd,
                __hip_bfloat16* __restrict__ wT1, __hip_bfloat16* __restrict__ wT2,
                __hip_bfloat16* __restrict__ wT3, __hip_bfloat16* __restrict__ wTa,
                __hip_bfloat16* __restrict__ wTd)
{
    const int bx = blockIdx.x, tid = threadIdx.x;
    if      (bx < 144) cast_one(w1, wT1,  64,  64, bx*256 + tid);
    else if (bx < 288) cast_one(w2, wT2,  64,  64, (bx-144)*256 + tid);
    else if (bx < 369) cast_one(w3, wT3,  36,  48, (bx-288)*256 + tid);
    else if (bx < 657) cast_one(wa, wTa, 128, 128, (bx-369)*256 + tid);
    else               cast_one(wd, wTd, 128, 128, (bx-657)*256 + tid);
}

// ---------------------------------------------------------------------------
// Implicit-GEMM 3x3 conv via MFMA, WIDE version: 512 threads (8 waves),
// 128-px full row per block -> weight staging + barriers amortized over 2x
// pixels vs the 64-px tile. Same per-thread register profile.
// ---------------------------------------------------------------------------
enum OutMode { OUT_NHWC_PAD_RELU, OUT_NCHW_F32, OUT_NCHW_BF16 };

template<int G, int CO_TOT, OutMode MODE>
__global__ __launch_bounds__(512)
void conv_mfma_k(const __hip_bfloat16* __restrict__ xT,
                 const __hip_bfloat16* __restrict__ wT, int o_total,
                 void* __restrict__ outp)
{
    __shared__ __hip_bfloat16 wA[G*16][64];
    const int tid = threadIdx.x, lane = tid & 63, wid = tid >> 6;  // wid 0..7
    const int l15 = lane & 15, khi = lane >> 4;
    const int oh = blockIdx.x;
    const int b = blockIdx.z & 7, cob = blockIdx.z >> 3;
    const int px = wid*16 + l15;            // 0..127 (full row)
    const __hip_bfloat16* xb = xT + (size_t)b*XPLANE_;

    f32x4 acc[G];
    const f32x4 vz = {0.f,0.f,0.f,0.f};
#pragma unroll
    for (int g=0; g<G; ++g) acc[g] = vz;

    for (int k=0; k<9; ++k){
        const int dy = k/3 - 1, dxk = k%3 - 1;
        __syncthreads();
        if (tid < G*16*8){
            const int o = tid >> 3, cs = tid & 7;
            *(bf16x8*)&wA[o][((cs ^ (o&7))*8)] =
                *(const bf16x8*)&wT[((size_t)k*o_total + cob*64 + o)*64 + cs*8];
        }
        __syncthreads();
        const int base = (((oh+1+dy)*WP_) + (px+1+dxk))*64;
#pragma unroll
        for (int s=0; s<2; ++s){
            const bf16x8 bfr = *(const bf16x8*)&xb[base + s*32 + khi*8];
            const int c8 = ((s*4 + khi) ^ (l15 & 7))*8;
#pragma unroll
            for (int g=0; g<G; ++g){
                const bf16x8 afr = *(const bf16x8*)&wA[g*16 + l15][c8];
                acc[g] = __builtin_amdgcn_mfma_f32_16x16x32_bf16(afr, bfr, acc[g], 0,0,0);
            }
        }
    }
    // ---- epilogue ----
    if (MODE == OUT_NHWC_PAD_RELU){
        __hip_bfloat16* ob = (__hip_bfloat16*)outp + (size_t)b*XPLANE_;
        const size_t orow = ((size_t)(oh+1)*WP_ + (px+1))*64;
#pragma unroll
        for (int g=0; g<G; ++g){
            union { short4 s4; __hip_bfloat16 h[4]; } o4;
#pragma unroll
            for (int r=0;r<4;r++) o4.h[r] = __float2bfloat16(fmaxf(acc[g][r], 0.f));
            *(short4*)&ob[orow + g*16 + khi*4] = o4.s4;
        }
    } else if (MODE == OUT_NCHW_F32){
        float* ob = (float*)outp;
#pragma unroll
        for (int g=0; g<G; ++g)
#pragma unroll
            for (int r=0;r<4;r++){
                const int co = cob*64 + g*16 + khi*4 + r;
                if (co < CO_TOT)
                    ob[(((size_t)b*CO_TOT + co)*H_ + oh)*W_ + px] = acc[g][r];
            }
    } else {
        __hip_bfloat16* ob = (__hip_bfloat16*)outp;
#pragma unroll
        for (int g=0; g<G; ++g)
#pragma unroll
            for (int r=0;r<4;r++){
                const int co = cob*64 + g*16 + khi*4 + r;
                ob[(((size_t)b*CO_TOT + co)*H_ + oh)*W_ + px] = __float2bfloat16(acc[g][r]);
            }
    }
}

// ---------------------------------------------------------------------------
// 4-corner bilinear blend of 8 consecutive channels (NHWC bf16) -> bf16x8.
// ---------------------------------------------------------------------------
__device__ __forceinline__ bf16x8 blend4(const __hip_bfloat16* __restrict__ xb,
                                         int a00, int dxo, int dro, float4 w)
{
    const u32x4 q00 = *(const u32x4*)(xb + a00);
    const u32x4 q01 = *(const u32x4*)(xb + a00 + dxo);
    const u32x4 q10 = *(const u32x4*)(xb + a00 + dro);
    const u32x4 q11 = *(const u32x4*)(xb + a00 + dro + dxo);
    union { bf16x8 v; __hip_bfloat16 h[8]; } R;
#pragma unroll
    for (int p=0;p<4;++p){
        const float l00 = __uint_as_float(q00[p]<<16), h00 = __uint_as_float(q00[p]&0xFFFF0000u);
        const float l01 = __uint_as_float(q01[p]<<16), h01 = __uint_as_float(q01[p]&0xFFFF0000u);
        const float l10 = __uint_as_float(q10[p]<<16), h10 = __uint_as_float(q10[p]&0xFFFF0000u);
        const float l11 = __uint_as_float(q11[p]<<16), h11 = __uint_as_float(q11[p]&0xFFFF0000u);
        R.h[2*p  ] = __float2bfloat16(w.x*l00 + w.y*l01 + w.z*l10 + w.w*l11);
        R.h[2*p+1] = __float2bfloat16(w.x*h00 + w.y*h01 + w.z*h10 + w.w*h11);
    }
    return R.v;
}

// ---------------------------------------------------------------------------
struct Meta { int a00, dxo, dro; float4 w4; };

__device__ __forceinline__ Meta mkmeta(int oh, int ow0, int px, int k,
                                       float oy, float ox)
{
    const int kr = k/3, kc = k - 3*kr;
    const float py  = (float)(oh  - 1 + kr) + oy;
    const float pxx = (float)(ow0 + px - 1 + kc) + ox;
    const float y0f = floorf(py), x0f = floorf(pxx);
    const float ay = py - y0f, ax = pxx - x0f;
    const int y0 = (int)y0f, x0 = (int)x0f;
    const int y1 = y0 + 1,   x1 = x0 + 1;
    const float my0 = (y0 >= 0 && y0 < H_) ? 1.f : 0.f;
    const float my1 = (y1 >= 0 && y1 < H_) ? 1.f : 0.f;
    const float mx0 = (x0 >= 0 && x0 < W_) ? 1.f : 0.f;
    const float mx1 = (x1 >= 0 && x1 < W_) ? 1.f : 0.f;
    const int y0c = min(max(y0,0),H_-1), y1c = min(max(y1,0),H_-1);
    const int x0c = min(max(x0,0),W_-1), x1c = min(max(x1,0),W_-1);
    const float wy0 = my0*(1.f-ay), wy1 = my1*ay;
    const float wx0 = mx0*(1.f-ax), wx1 = mx1*ax;
    Meta m;
    m.a00 = ((y0c+1)*WP_ + (x0c+1))*64;
    m.dxo = (x1c-x0c)*64;
    m.dro = (y1c-y0c)*WP_*64;
    m.w4  = make_float4(wy0*wx0, wy0*wx1, wy1*wx0, wy1*wx1);
    return m;
}

// ---------------------------------------------------------------------------
// Fused deformable conv (MFMA) + softmax attention (R7 best, byte-identical):
// tap-outer/dk-inner, double-buffered wA, async-split staging, 9 barriers.
// Gather-stream floor ~125us (R9 ablation); this kernel sits ~20% above it.
// ---------------------------------------------------------------------------
__global__ __launch_bounds__(256)
void deform_att_k(const __hip_bfloat16* __restrict__ xT,
                  const float* __restrict__ off,
                  const __hip_bfloat16* __restrict__ att,
                  const __hip_bfloat16* __restrict__ wTd,   // [9][128][64]
                  float* __restrict__ out)
{
    __shared__ __hip_bfloat16 wA[2][2][64][64];   // [buf][dk][co][c]
    const int tid = threadIdx.x, lane = tid & 63, wid = tid >> 6;
    const int l15 = lane & 15, khi = lane >> 4;
    const int ow0 = blockIdx.x*64, oh = blockIdx.y, b = blockIdx.z;
    const int px = wid*16 + l15;
    const __hip_bfloat16* xb = xT + (size_t)b*XPLANE_;
    const float* offb = off + (size_t)b*36*HW_ + (size_t)oh*W_ + ow0 + px;
    const int srow = tid >> 3, scs = tid & 7;
    const int swz = (scs ^ (srow & 7)) * 8;

    f32x4 acc[2][4];
    const f32x4 vz = {0.f,0.f,0.f,0.f};
#pragma unroll
    for (int d=0; d<2; ++d)
#pragma unroll
        for (int g=0; g<4; ++g) acc[d][g] = vz;

    {
        const __hip_bfloat16* ws0 = &wTd[(size_t)srow*64 + scs*8];
        *(bf16x8*)&wA[0][0][srow   ][swz] = *(const bf16x8*)ws0;
        *(bf16x8*)&wA[0][0][srow+32][swz] = *(const bf16x8*)(ws0 + 32*64);
        *(bf16x8*)&wA[0][1][srow   ][swz] = *(const bf16x8*)(ws0 + 64*64);
        *(bf16x8*)&wA[0][1][srow+32][swz] = *(const bf16x8*)(ws0 + 96*64);
    }
    float oyr0 = offb[0],                 oxr0 = offb[HW_];
    float oyr1 = offb[(size_t)18*HW_],    oxr1 = offb[(size_t)19*HW_];
    __syncthreads();

    for (int k=0; k<9; ++k){
        bf16x8 nw00 = {}, nw01 = {}, nw10 = {}, nw11 = {};
        float noy0=0.f, nox0=0.f, noy1=0.f, nox1=0.f;
        const bool hn = (k < 8);
        if (hn){
            const __hip_bfloat16* ws0 = &wTd[((size_t)(k+1)*128 + srow)*64 + scs*8];
            nw00 = *(const bf16x8*)ws0;
            nw01 = *(const bf16x8*)(ws0 + 32*64);
            nw10 = *(const bf16x8*)(ws0 + 64*64);
            nw11 = *(const bf16x8*)(ws0 + 96*64);
            noy0 = offb[(size_t)(2*k+2)*HW_];
            nox0 = offb[(size_t)(2*k+3)*HW_];
            noy1 = offb[(size_t)(2*k+20)*HW_];
            nox1 = offb[(size_t)(2*k+21)*HW_];
        }
        const Meta m0 = mkmeta(oh, ow0, px, k, oyr0, oxr0);
        const Meta m1 = mkmeta(oh, ow0, px, k, oyr1, oxr1);
        const __hip_bfloat16 (*wr0)[64] = (const __hip_bfloat16 (*)[64])wA[k & 1][0];
        const __hip_bfloat16 (*wr1)[64] = (const __hip_bfloat16 (*)[64])wA[k & 1][1];
#pragma unroll
        for (int s=0; s<2; ++s){
            const bf16x8 b0 = blend4(xb, m0.a00 + s*32 + khi*8, m0.dxo, m0.dro, m0.w4);
            const bf16x8 b1 = blend4(xb, m1.a00 + s*32 + khi*8, m1.dxo, m1.dro, m1.w4);
            const int c8 = ((s*4 + khi) ^ (l15 & 7))*8;
#pragma unroll
            for (int g=0; g<4; ++g){
                const bf16x8 a0 = *(const bf16x8*)&wr0[g*16 + l15][c8];
                acc[0][g] = __builtin_amdgcn_mfma_f32_16x16x32_bf16(a0, b0, acc[0][g], 0,0,0);
            }
#pragma unroll
            for (int g=0; g<4; ++g){
                const bf16x8 a1 = *(const bf16x8*)&wr1[g*16 + l15][c8];
                acc[1][g] = __builtin_amdgcn_mfma_f32_16x16x32_bf16(a1, b1, acc[1][g], 0,0,0);
            }
        }
        if (hn){
            *(bf16x8*)&wA[(k+1)&1][0][srow   ][swz] = nw00;
            *(bf16x8*)&wA[(k+1)&1][0][srow+32][swz] = nw01;
            *(bf16x8*)&wA[(k+1)&1][1][srow   ][swz] = nw10;
            *(bf16x8*)&wA[(k+1)&1][1][srow+32][swz] = nw11;
            oyr0 = noy0; oxr0 = nox0; oyr1 = noy1; oxr1 = nox1;
        }
        __syncthreads();
    }
#pragma unroll
    for (int g=0; g<4; ++g)
#pragma unroll
        for (int r=0; r<4; ++r){
            const int co = g*16 + khi*4 + r;
            const float a0 = __bfloat162float(att[(((size_t)b*128      + co)*H_ + oh)*W_ + ow0 + px]);
            const float a1 = __bfloat162float(att[(((size_t)b*128 + 64 + co)*H_ + oh)*W_ + ow0 + px]);
            const float f0 = 1.f / (1.f + __expf(a1 - a0));
            out[(((size_t)b*64 + co)*H_ + oh)*W_ + ow0 + px] =
                acc[0][g][r]*f0 + acc[1][g][r]*(1.f - f0);
        }
}

// ---------------------------------------------------------------------------
extern "C" void kernel_launch(void* const* d_in, const int* in_sizes, int n_in,
                              void* d_out, int out_size, void* d_ws, size_t ws_size,
                              hipStream_t stream)
{
    const float* x  = (const float*)d_in[0];
    const float* w1 = (const float*)d_in[1];
    const float* w2 = (const float*)d_in[2];
    const float* w3 = (const float*)d_in[3];
    const float* wa = (const float*)d_in[4];
    const float* wd = (const float*)d_in[5];
    float* out = (float*)d_out;

    // ---- workspace layout (halfword units for bf16 regions) ----
    __hip_bfloat16* xTp  = (__hip_bfloat16*)d_ws;       // 8,652,800
    __hip_bfloat16* m1Tp = xTp  + (size_t)8652800;      // 8,652,800
    __hip_bfloat16* m2Tp = m1Tp + (size_t)8652800;      // 8,652,800
    __hip_bfloat16* wT1  = m2Tp + (size_t)8652800;      // 36864
    __hip_bfloat16* wT2  = wT1  + 36864;                // 36864
    __hip_bfloat16* wT3  = wT2  + 36864;                // 27648
    __hip_bfloat16* wTa  = wT3  + 27648;                // 73728
    __hip_bfloat16* wTd  = wTa  + 73728;                // 73728
    float*          offs = (float*)(wTd + 73728);       // 4,718,592 fp32
    __hip_bfloat16* att16 = m1Tp;   // aliases m1Tp+m2Tp (both dead by then)

    const dim3 blk(256);
    const dim3 blkw(512);
    zero_halo_k<<<dim3(25), blk, 0, stream>>>((unsigned int*)xTp, (unsigned int*)wT3);
    xpose_x_k<<<dim3(2,128,8), blk, 0, stream>>>(x, xTp);
    cast_all_k<<<dim3(945), blk, 0, stream>>>(w1,w2,w3,wa,wd, wT1,wT2,wT3,wTa,wTd);
    // conv chain (implicit-GEMM MFMA, wide 128-px rows, 8 waves)
    conv_mfma_k<4,  64, OUT_NHWC_PAD_RELU><<<dim3(128,1,8),  blkw, 0, stream>>>(xTp,  wT1,  64, m1Tp);
    conv_mfma_k<4,  64, OUT_NHWC_PAD_RELU><<<dim3(128,1,8),  blkw, 0, stream>>>(m1Tp, wT2,  64, m2Tp);
    conv_mfma_k<3,  36, OUT_NCHW_F32     ><<<dim3(128,1,8),  blkw, 0, stream>>>(m2Tp, wT3,  48, offs);
    conv_mfma_k<4, 128, OUT_NCHW_BF16    ><<<dim3(128,1,16), blkw, 0, stream>>>(xTp,  wTa, 128, att16);
    // fused deformable conv + attention (R7-best, unchanged)
    deform_att_k<<<dim3(2,128,8), blk, 0, stream>>>(xTp, offs, att16, wTd, out);
}

// Round 12
// 274.131 us; speedup vs baseline: 2.4023x; 1.0258x over previous
//
#include <hip/hip_runtime.h>
#include <hip/hip_bf16.h>
#include <math.h>

#define B_ 8
#define C_ 64
#define H_ 128
#define W_ 128
#define HW_ (H_*W_)
#define HP_ 130
#define WP_ 130
#define XPLANE_ (HP_*WP_*64)     // padded NHWC plane per batch (halfwords)

typedef __attribute__((ext_vector_type(8))) short bf16x8;
typedef __attribute__((ext_vector_type(4))) float f32x4;
typedef __attribute__((ext_vector_type(4))) unsigned int u32x4;

// ---------------------------------------------------------------------------
// Weight transpose+cast helper: w fp32 [O][64][9] -> wT bf16 [9][OPAD][64]
// ---------------------------------------------------------------------------
__device__ __forceinline__ void cast_one(const float* __restrict__ w,
                                         __hip_bfloat16* __restrict__ wT,
                                         int O, int OPAD, int idx)
{
    if (idx >= 9*O*64) return;
    const int k = idx / (O*64);
    const int rem = idx - k*O*64;
    const int o = rem >> 6, c = rem & 63;
    wT[((size_t)k*OPAD + o)*64 + c] = __float2bfloat16(w[((size_t)o*64 + c)*9 + k]);
}

// ---------------------------------------------------------------------------
// PREP (one launch): halo zeroing (blocks 0..23), wT3 pad-row zeroing (24),
// all weight casts (25..969), x NCHW fp32 -> padded NHWC bf16 (970..3017).
// ---------------------------------------------------------------------------
__global__ __launch_bounds__(256)
void prep_k(const float* __restrict__ x,
            const float* __restrict__ w1, const float* __restrict__ w2,
            const float* __restrict__ w3, const float* __restrict__ wa,
            const float* __restrict__ wd,
            __hip_bfloat16* __restrict__ xTp, __hip_bfloat16* __restrict__ m1Tp,
            __hip_bfloat16* __restrict__ m2Tp,
            __hip_bfloat16* __restrict__ wT1, __hip_bfloat16* __restrict__ wT2,
            __hip_bfloat16* __restrict__ wT3, __hip_bfloat16* __restrict__ wTa,
            __hip_bfloat16* __restrict__ wTd)
{
    __shared__ float tile[64][65];
    const int bx = blockIdx.x, tid = threadIdx.x;
    if (bx < 24){
        // 1-px halo ring of the 3 padded NHWC planes
        const int plane = bx >> 3, batch = bx & 7;
        __hip_bfloat16* pl = (plane==0) ? xTp : ((plane==1) ? m1Tp : m2Tp);
        unsigned int* base = (unsigned int*)pl + (size_t)batch*(XPLANE_/2);
        for (int i = tid; i < 516*32; i += 256){
            const int u = i & 31, p = i >> 5;
            int h, w;
            if (p < 130)      { h = 0;        w = p;       }
            else if (p < 260) { h = 129;      w = p - 130; }
            else if (p < 388) { h = p - 259;  w = 0;       }
            else              { h = p - 387;  w = 129;     }
            base[(size_t)(h*130 + w)*32 + u] = 0u;
        }
    } else if (bx == 24){
        // wT3 pad rows only (o in [36,48)) -- cast writes o<36 concurrently
        unsigned int* w3u = (unsigned int*)wT3;
        for (int i = tid; i < 3456; i += 256){
            const int k = i / 384, rem = i - k*384;
            w3u[k*1536 + 1152 + rem] = 0u;
        }
    } else if (bx < 970){
        const int cbx = bx - 25;
        if      (cbx < 144) cast_one(w1, wT1,  64,  64, cbx*256 + tid);
        else if (cbx < 288) cast_one(w2, wT2,  64,  64, (cbx-144)*256 + tid);
        else if (cbx < 369) cast_one(w3, wT3,  36,  48, (cbx-288)*256 + tid);
        else if (cbx < 657) cast_one(wa, wTa, 128, 128, (cbx-369)*256 + tid);
        else                cast_one(wd, wTd, 128, 128, (cbx-657)*256 + tid);
    } else {
        // xpose: 2048 sub-blocks
        const int i = bx - 970;
        const int w0 = (i & 1)*64, h = (i >> 1) & 127, b = i >> 8;
        const float* xb = x + (size_t)b*64*HW_;
        for (int j = tid; j < 4096; j += 256){
            const int c = j >> 6, px = j & 63;
            tile[c][px] = xb[(size_t)c*HW_ + h*W_ + w0 + px];
        }
        __syncthreads();
        __hip_bfloat16* ob = xTp + (size_t)b*XPLANE_;
        for (int j = tid; j < 512; j += 256){
            const int px = j >> 3, cs = j & 7;
            union { bf16x8 v; __hip_bfloat16 h8[8]; } R;
#pragma unroll
            for (int q=0;q<8;q++) R.h8[q] = __float2bfloat16(tile[cs*8+q][px]);
            *(bf16x8*)&ob[((size_t)(h+1)*WP_ + (w0+px+1))*64 + cs*8] = R.v;
        }
    }
}

// ---------------------------------------------------------------------------
// Implicit-GEMM 3x3 conv via MFMA, wide: 512 threads, 128-px full row/block.
// ---------------------------------------------------------------------------
template<int G>
__global__ __launch_bounds__(512)
void conv_mfma_k(const __hip_bfloat16* __restrict__ xT,
                 const __hip_bfloat16* __restrict__ wT, int o_total,
                 __hip_bfloat16* __restrict__ outp)   // NHWC padded + ReLU
{
    __shared__ __hip_bfloat16 wA[G*16][64];
    const int tid = threadIdx.x, lane = tid & 63, wid = tid >> 6;
    const int l15 = lane & 15, khi = lane >> 4;
    const int oh = blockIdx.x;
    const int b = blockIdx.z;
    const int px = wid*16 + l15;
    const __hip_bfloat16* xb = xT + (size_t)b*XPLANE_;

    f32x4 acc[G];
    const f32x4 vz = {0.f,0.f,0.f,0.f};
#pragma unroll
    for (int g=0; g<G; ++g) acc[g] = vz;

    for (int k=0; k<9; ++k){
        const int dy = k/3 - 1, dxk = k%3 - 1;
        __syncthreads();
        if (tid < G*16*8){
            const int o = tid >> 3, cs = tid & 7;
            *(bf16x8*)&wA[o][((cs ^ (o&7))*8)] =
                *(const bf16x8*)&wT[((size_t)k*o_total + o)*64 + cs*8];
        }
        __syncthreads();
        const int base = (((oh+1+dy)*WP_) + (px+1+dxk))*64;
#pragma unroll
        for (int s=0; s<2; ++s){
            const bf16x8 bfr = *(const bf16x8*)&xb[base + s*32 + khi*8];
            const int c8 = ((s*4 + khi) ^ (l15 & 7))*8;
#pragma unroll
            for (int g=0; g<G; ++g){
                const bf16x8 afr = *(const bf16x8*)&wA[g*16 + l15][c8];
                acc[g] = __builtin_amdgcn_mfma_f32_16x16x32_bf16(afr, bfr, acc[g], 0,0,0);
            }
        }
    }
    __hip_bfloat16* ob = outp + (size_t)b*XPLANE_;
    const size_t orow = ((size_t)(oh+1)*WP_ + (px+1))*64;
#pragma unroll
    for (int g=0; g<G; ++g){
        union { short4 s4; __hip_bfloat16 h[4]; } o4;
#pragma unroll
        for (int r=0;r<4;r++) o4.h[r] = __float2bfloat16(fmaxf(acc[g][r], 0.f));
        *(short4*)&ob[orow + g*16 + khi*4] = o4.s4;
    }
}

// ---------------------------------------------------------------------------
// MERGED K3: z<8 -> offs conv (m2 -> offsb bf16 NCHW, 36 ch);
//            z>=8 -> att conv (x -> attn bf16 NHWC-128).
// att is independent of m2, so its ~2x work hides conv3 entirely.
// ---------------------------------------------------------------------------
__global__ __launch_bounds__(512)
void conv3_att_k(const __hip_bfloat16* __restrict__ m2T,
                 const __hip_bfloat16* __restrict__ xT,
                 const __hip_bfloat16* __restrict__ wT3,   // [9][48][64]
                 const __hip_bfloat16* __restrict__ wTa,   // [9][128][64]
                 __hip_bfloat16* __restrict__ offsb,       // [b][36][128][128]
                 __hip_bfloat16* __restrict__ attn)        // [b][h][w][128]
{
    __shared__ __hip_bfloat16 wA[64][64];
    const int tid = threadIdx.x, lane = tid & 63, wid = tid >> 6;
    const int l15 = lane & 15, khi = lane >> 4;
    const int oh = blockIdx.x;
    const int px = wid*16 + l15;
    const f32x4 vz = {0.f,0.f,0.f,0.f};

    if (blockIdx.z < 8){
        // ---- offs conv: G=3, CO=36 (pad 48) ----
        const int b = blockIdx.z;
        const __hip_bfloat16* xb = m2T + (size_t)b*XPLANE_;
        f32x4 acc[3];
#pragma unroll
        for (int g=0; g<3; ++g) acc[g] = vz;
        for (int k=0; k<9; ++k){
            const int dy = k/3 - 1, dxk = k%3 - 1;
            __syncthreads();
            if (tid < 384){
                const int o = tid >> 3, cs = tid & 7;
                *(bf16x8*)&wA[o][((cs ^ (o&7))*8)] =
                    *(const bf16x8*)&wT3[((size_t)k*48 + o)*64 + cs*8];
            }
            __syncthreads();
            const int base = (((oh+1+dy)*WP_) + (px+1+dxk))*64;
#pragma unroll
            for (int s=0; s<2; ++s){
                const bf16x8 bfr = *(const bf16x8*)&xb[base + s*32 + khi*8];
                const int c8 = ((s*4 + khi) ^ (l15 & 7))*8;
#pragma unroll
                for (int g=0; g<3; ++g){
                    const bf16x8 afr = *(const bf16x8*)&wA[g*16 + l15][c8];
                    acc[g] = __builtin_amdgcn_mfma_f32_16x16x32_bf16(afr, bfr, acc[g], 0,0,0);
                }
            }
        }
#pragma unroll
        for (int g=0; g<3; ++g)
#pragma unroll
            for (int r=0;r<4;r++){
                const int co = g*16 + khi*4 + r;
                if (co < 36)
                    offsb[(((size_t)b*36 + co)*H_ + oh)*W_ + px] =
                        __float2bfloat16(acc[g][r]);
            }
    } else {
        // ---- att conv: G=4, 64 co per dkb, NHWC-128 output ----
        const int zz = blockIdx.z - 8, b = zz & 7, dkb = zz >> 3;
        const __hip_bfloat16* xb = xT + (size_t)b*XPLANE_;
        f32x4 acc[4];
#pragma unroll
        for (int g=0; g<4; ++g) acc[g] = vz;
        for (int k=0; k<9; ++k){
            const int dy = k/3 - 1, dxk = k%3 - 1;
            __syncthreads();
            {
                const int o = tid >> 3, cs = tid & 7;
                *(bf16x8*)&wA[o][((cs ^ (o&7))*8)] =
                    *(const bf16x8*)&wTa[((size_t)k*128 + dkb*64 + o)*64 + cs*8];
            }
            __syncthreads();
            const int base = (((oh+1+dy)*WP_) + (px+1+dxk))*64;
#pragma unroll
            for (int s=0; s<2; ++s){
                const bf16x8 bfr = *(const bf16x8*)&xb[base + s*32 + khi*8];
                const int c8 = ((s*4 + khi) ^ (l15 & 7))*8;
#pragma unroll
                for (int g=0; g<4; ++g){
                    const bf16x8 afr = *(const bf16x8*)&wA[g*16 + l15][c8];
                    acc[g] = __builtin_amdgcn_mfma_f32_16x16x32_bf16(afr, bfr, acc[g], 0,0,0);
                }
            }
        }
        __hip_bfloat16* ab = attn + ((size_t)b*HW_ + (size_t)oh*W_ + px)*128 + dkb*64;
#pragma unroll
        for (int g=0; g<4; ++g){
            union { short4 s4; __hip_bfloat16 h[4]; } o4;
#pragma unroll
            for (int r=0;r<4;r++) o4.h[r] = __float2bfloat16(acc[g][r]);
            *(short4*)&ab[g*16 + khi*4] = o4.s4;
        }
    }
}

// ---------------------------------------------------------------------------
// 4-corner bilinear blend of 8 consecutive channels (NHWC bf16) -> bf16x8.
// ---------------------------------------------------------------------------
__device__ __forceinline__ bf16x8 blend4(const __hip_bfloat16* __restrict__ xb,
                                         int a00, int dxo, int dro, float4 w)
{
    const u32x4 q00 = *(const u32x4*)(xb + a00);
    const u32x4 q01 = *(const u32x4*)(xb + a00 + dxo);
    const u32x4 q10 = *(const u32x4*)(xb + a00 + dro);
    const u32x4 q11 = *(const u32x4*)(xb + a00 + dro + dxo);
    union { bf16x8 v; __hip_bfloat16 h[8]; } R;
#pragma unroll
    for (int p=0;p<4;++p){
        const float l00 = __uint_as_float(q00[p]<<16), h00 = __uint_as_float(q00[p]&0xFFFF0000u);
        const float l01 = __uint_as_float(q01[p]<<16), h01 = __uint_as_float(q01[p]&0xFFFF0000u);
        const float l10 = __uint_as_float(q10[p]<<16), h10 = __uint_as_float(q10[p]&0xFFFF0000u);
        const float l11 = __uint_as_float(q11[p]<<16), h11 = __uint_as_float(q11[p]&0xFFFF0000u);
        R.h[2*p  ] = __float2bfloat16(w.x*l00 + w.y*l01 + w.z*l10 + w.w*l11);
        R.h[2*p+1] = __float2bfloat16(w.x*h00 + w.y*h01 + w.z*h10 + w.w*h11);
    }
    return R.v;
}

// ---------------------------------------------------------------------------
struct Meta { int a00, dxo, dro; float4 w4; };

__device__ __forceinline__ Meta mkmeta(int oh, int ow0, int px, int k,
                                       float oy, float ox)
{
    const int kr = k/3, kc = k - 3*kr;
    const float py  = (float)(oh  - 1 + kr) + oy;
    const float pxx = (float)(ow0 + px - 1 + kc) + ox;
    const float y0f = floorf(py), x0f = floorf(pxx);
    const float ay = py - y0f, ax = pxx - x0f;
    const int y0 = (int)y0f, x0 = (int)x0f;
    const int y1 = y0 + 1,   x1 = x0 + 1;
    const float my0 = (y0 >= 0 && y0 < H_) ? 1.f : 0.f;
    const float my1 = (y1 >= 0 && y1 < H_) ? 1.f : 0.f;
    const float mx0 = (x0 >= 0 && x0 < W_) ? 1.f : 0.f;
    const float mx1 = (x1 >= 0 && x1 < W_) ? 1.f : 0.f;
    const int y0c = min(max(y0,0),H_-1), y1c = min(max(y1,0),H_-1);
    const int x0c = min(max(x0,0),W_-1), x1c = min(max(x1,0),W_-1);
    const float wy0 = my0*(1.f-ay), wy1 = my1*ay;
    const float wx0 = mx0*(1.f-ax), wx1 = mx1*ax;
    Meta m;
    m.a00 = ((y0c+1)*WP_ + (x0c+1))*64;
    m.dxo = (x1c-x0c)*64;
    m.dro = (y1c-y0c)*WP_*64;
    m.w4  = make_float4(wy0*wx0, wy0*wx1, wy1*wx0, wy1*wx1);
    return m;
}

// ---------------------------------------------------------------------------
// Fused deformable conv (MFMA) + softmax attention (R7-best structure):
// changes vs R11: bf16 offset loads; NHWC-128 att reads (8x8B vs 32x2B).
// Gather-stream floor ~125us (R9 ablation).
// ---------------------------------------------------------------------------
__global__ __launch_bounds__(256)
void deform_att_k(const __hip_bfloat16* __restrict__ xT,
                  const __hip_bfloat16* __restrict__ offsb,
                  const __hip_bfloat16* __restrict__ attn,
                  const __hip_bfloat16* __restrict__ wTd,   // [9][128][64]
                  float* __restrict__ out)
{
    __shared__ __hip_bfloat16 wA[2][2][64][64];   // [buf][dk][co][c]
    const int tid = threadIdx.x, lane = tid & 63, wid = tid >> 6;
    const int l15 = lane & 15, khi = lane >> 4;
    const int ow0 = blockIdx.x*64, oh = blockIdx.y, b = blockIdx.z;
    const int px = wid*16 + l15;
    const __hip_bfloat16* xb = xT + (size_t)b*XPLANE_;
    const __hip_bfloat16* offb = offsb + (size_t)b*36*HW_ + (size_t)oh*W_ + ow0 + px;
    const int srow = tid >> 3, scs = tid & 7;
    const int swz = (scs ^ (srow & 7)) * 8;

    f32x4 acc[2][4];
    const f32x4 vz = {0.f,0.f,0.f,0.f};
#pragma unroll
    for (int d=0; d<2; ++d)
#pragma unroll
        for (int g=0; g<4; ++g) acc[d][g] = vz;

    {
        const __hip_bfloat16* ws0 = &wTd[(size_t)srow*64 + scs*8];
        *(bf16x8*)&wA[0][0][srow   ][swz] = *(const bf16x8*)ws0;
        *(bf16x8*)&wA[0][0][srow+32][swz] = *(const bf16x8*)(ws0 + 32*64);
        *(bf16x8*)&wA[0][1][srow   ][swz] = *(const bf16x8*)(ws0 + 64*64);
        *(bf16x8*)&wA[0][1][srow+32][swz] = *(const bf16x8*)(ws0 + 96*64);
    }
    float oyr0 = __bfloat162float(offb[0]);
    float oxr0 = __bfloat162float(offb[HW_]);
    float oyr1 = __bfloat162float(offb[(size_t)18*HW_]);
    float oxr1 = __bfloat162float(offb[(size_t)19*HW_]);
    __syncthreads();

    for (int k=0; k<9; ++k){
        bf16x8 nw00 = {}, nw01 = {}, nw10 = {}, nw11 = {};
        float noy0=0.f, nox0=0.f, noy1=0.f, nox1=0.f;
        const bool hn = (k < 8);
        if (hn){
            const __hip_bfloat16* ws0 = &wTd[((size_t)(k+1)*128 + srow)*64 + scs*8];
            nw00 = *(const bf16x8*)ws0;
            nw01 = *(const bf16x8*)(ws0 + 32*64);
            nw10 = *(const bf16x8*)(ws0 + 64*64);
            nw11 = *(const bf16x8*)(ws0 + 96*64);
            noy0 = __bfloat162float(offb[(size_t)(2*k+2)*HW_]);
            nox0 = __bfloat162float(offb[(size_t)(2*k+3)*HW_]);
            noy1 = __bfloat162float(offb[(size_t)(2*k+20)*HW_]);
            nox1 = __bfloat162float(offb[(size_t)(2*k+21)*HW_]);
        }
        const Meta m0 = mkmeta(oh, ow0, px, k, oyr0, oxr0);
        const Meta m1 = mkmeta(oh, ow0, px, k, oyr1, oxr1);
        const __hip_bfloat16 (*wr0)[64] = (const __hip_bfloat16 (*)[64])wA[k & 1][0];
        const __hip_bfloat16 (*wr1)[64] = (const __hip_bfloat16 (*)[64])wA[k & 1][1];
#pragma unroll
        for (int s=0; s<2; ++s){
            const bf16x8 b0 = blend4(xb, m0.a00 + s*32 + khi*8, m0.dxo, m0.dro, m0.w4);
            const bf16x8 b1 = blend4(xb, m1.a00 + s*32 + khi*8, m1.dxo, m1.dro, m1.w4);
            const int c8 = ((s*4 + khi) ^ (l15 & 7))*8;
#pragma unroll
            for (int g=0; g<4; ++g){
                const bf16x8 a0 = *(const bf16x8*)&wr0[g*16 + l15][c8];
                acc[0][g] = __builtin_amdgcn_mfma_f32_16x16x32_bf16(a0, b0, acc[0][g], 0,0,0);
            }
#pragma unroll
            for (int g=0; g<4; ++g){
                const bf16x8 a1 = *(const bf16x8*)&wr1[g*16 + l15][c8];
                acc[1][g] = __builtin_amdgcn_mfma_f32_16x16x32_bf16(a1, b1, acc[1][g], 0,0,0);
            }
        }
        if (hn){
            *(bf16x8*)&wA[(k+1)&1][0][srow   ][swz] = nw00;
            *(bf16x8*)&wA[(k+1)&1][0][srow+32][swz] = nw01;
            *(bf16x8*)&wA[(k+1)&1][1][srow   ][swz] = nw10;
            *(bf16x8*)&wA[(k+1)&1][1][srow+32][swz] = nw11;
            oyr0 = noy0; oxr0 = nox0; oyr1 = noy1; oxr1 = nox1;
        }
        __syncthreads();
    }
    // ---- epilogue: NHWC-128 att reads (8B each) + softmax + write ----
    const __hip_bfloat16* ab = attn + ((size_t)b*HW_ + (size_t)oh*W_ + ow0 + px)*128;
#pragma unroll
    for (int g=0; g<4; ++g){
        union { short4 s4; __hip_bfloat16 h[4]; } a0v, a1v;
        a0v.s4 = *(const short4*)&ab[     g*16 + khi*4];
        a1v.s4 = *(const short4*)&ab[64 + g*16 + khi*4];
#pragma unroll
        for (int r=0; r<4; ++r){
            const int co = g*16 + khi*4 + r;
            const float a0 = __bfloat162float(a0v.h[r]);
            const float a1 = __bfloat162float(a1v.h[r]);
            const float f0 = 1.f / (1.f + __expf(a1 - a0));
            out[(((size_t)b*64 + co)*H_ + oh)*W_ + ow0 + px] =
                acc[0][g][r]*f0 + acc[1][g][r]*(1.f - f0);
        }
    }
}

// ---------------------------------------------------------------------------
extern "C" void kernel_launch(void* const* d_in, const int* in_sizes, int n_in,
                              void* d_out, int out_size, void* d_ws, size_t ws_size,
                              hipStream_t stream)
{
    const float* x  = (const float*)d_in[0];
    const float* w1 = (const float*)d_in[1];
    const float* w2 = (const float*)d_in[2];
    const float* w3 = (const float*)d_in[3];
    const float* wa = (const float*)d_in[4];
    const float* wd = (const float*)d_in[5];
    float* out = (float*)d_out;

    // ---- workspace layout (halfword units), total 39,050,240 hw = 78.1 MB ----
    __hip_bfloat16* xTp   = (__hip_bfloat16*)d_ws;       // 8,652,800
    __hip_bfloat16* m2Tp  = xTp   + (size_t)8652800;     // 8,652,800
    __hip_bfloat16* wT1   = m2Tp  + (size_t)8652800;     // 36864
    __hip_bfloat16* wT2   = wT1   + 36864;               // 36864
    __hip_bfloat16* wT3   = wT2   + 36864;               // 27648
    __hip_bfloat16* wTa   = wT3   + 27648;               // 73728
    __hip_bfloat16* wTd   = wTa   + 73728;               // 73728
    __hip_bfloat16* offsb = wTd   + 73728;               // 4,718,592 (bf16 NCHW)
    __hip_bfloat16* m1Tp  = offsb + (size_t)4718592;     // 8,652,800
    __hip_bfloat16* attn  = m1Tp;                        // 16,777,216 (m1 dead + tail)

    const dim3 blk(256), blkw(512);
    // prep: halos + weight casts + x transpose (one launch)
    prep_k<<<dim3(3018), blk, 0, stream>>>(x, w1,w2,w3,wa,wd,
                                           xTp, m1Tp, m2Tp,
                                           wT1, wT2, wT3, wTa, wTd);
    // conv chain
    conv_mfma_k<4><<<dim3(128,1,8), blkw, 0, stream>>>(xTp,  wT1, 64, m1Tp);
    conv_mfma_k<4><<<dim3(128,1,8), blkw, 0, stream>>>(m1Tp, wT2, 64, m2Tp);
    // merged: offs conv (z<8) + att conv (z>=8); att independent of m2
    conv3_att_k<<<dim3(128,1,24), blkw, 0, stream>>>(m2Tp, xTp, wT3, wTa,
                                                     offsb, attn);
    // fused deformable conv + attention
    deform_att_k<<<dim3(2,128,8), blk, 0, stream>>>(xTp, offsb, attn, wTd, out);
}

// Round 13
// 213.671 us; speedup vs baseline: 3.0821x; 1.2830x over previous
//
#include <hip/hip_runtime.h>
#include <hip/hip_bf16.h>
#include <math.h>

#define B_ 8
#define C_ 64
#define H_ 128
#define W_ 128
#define HW_ (H_*W_)
#define HP_ 130
#define WP_ 130
#define XPLANE_ (HP_*WP_*64)     // padded NHWC plane per batch (halfwords)

typedef __attribute__((ext_vector_type(8))) short bf16x8;
typedef __attribute__((ext_vector_type(4))) float f32x4;
typedef __attribute__((ext_vector_type(4))) unsigned int u32x4;

// ---------------------------------------------------------------------------
// Weight transpose+cast helper: w fp32 [O][64][9] -> wT bf16 [9][OPAD][64]
// ---------------------------------------------------------------------------
__device__ __forceinline__ void cast_one(const float* __restrict__ w,
                                         __hip_bfloat16* __restrict__ wT,
                                         int O, int OPAD, int idx)
{
    if (idx >= 9*O*64) return;
    const int k = idx / (O*64);
    const int rem = idx - k*O*64;
    const int o = rem >> 6, c = rem & 63;
    wT[((size_t)k*OPAD + o)*64 + c] = __float2bfloat16(w[((size_t)o*64 + c)*9 + k]);
}

// ---------------------------------------------------------------------------
// PREP (one launch): halo zeroing (blocks 0..23), wT3 pad-row zeroing (24),
// all weight casts (25..969), x NCHW fp32 -> padded NHWC bf16 (970..3017).
// ---------------------------------------------------------------------------
__global__ __launch_bounds__(256)
void prep_k(const float* __restrict__ x,
            const float* __restrict__ w1, const float* __restrict__ w2,
            const float* __restrict__ w3, const float* __restrict__ wa,
            const float* __restrict__ wd,
            __hip_bfloat16* __restrict__ xTp, __hip_bfloat16* __restrict__ m1Tp,
            __hip_bfloat16* __restrict__ m2Tp,
            __hip_bfloat16* __restrict__ wT1, __hip_bfloat16* __restrict__ wT2,
            __hip_bfloat16* __restrict__ wT3, __hip_bfloat16* __restrict__ wTa,
            __hip_bfloat16* __restrict__ wTd)
{
    __shared__ float tile[64][65];
    const int bx = blockIdx.x, tid = threadIdx.x;
    if (bx < 24){
        const int plane = bx >> 3, batch = bx & 7;
        __hip_bfloat16* pl = (plane==0) ? xTp : ((plane==1) ? m1Tp : m2Tp);
        unsigned int* base = (unsigned int*)pl + (size_t)batch*(XPLANE_/2);
        for (int i = tid; i < 516*32; i += 256){
            const int u = i & 31, p = i >> 5;
            int h, w;
            if (p < 130)      { h = 0;        w = p;       }
            else if (p < 260) { h = 129;      w = p - 130; }
            else if (p < 388) { h = p - 259;  w = 0;       }
            else              { h = p - 387;  w = 129;     }
            base[(size_t)(h*130 + w)*32 + u] = 0u;
        }
    } else if (bx == 24){
        unsigned int* w3u = (unsigned int*)wT3;
        for (int i = tid; i < 3456; i += 256){
            const int k = i / 384, rem = i - k*384;
            w3u[k*1536 + 1152 + rem] = 0u;
        }
    } else if (bx < 970){
        const int cbx = bx - 25;
        if      (cbx < 144) cast_one(w1, wT1,  64,  64, cbx*256 + tid);
        else if (cbx < 288) cast_one(w2, wT2,  64,  64, (cbx-144)*256 + tid);
        else if (cbx < 369) cast_one(w3, wT3,  36,  48, (cbx-288)*256 + tid);
        else if (cbx < 657) cast_one(wa, wTa, 128, 128, (cbx-369)*256 + tid);
        else                cast_one(wd, wTd, 128, 128, (cbx-657)*256 + tid);
    } else {
        const int i = bx - 970;
        const int w0 = (i & 1)*64, h = (i >> 1) & 127, b = i >> 8;
        const float* xb = x + (size_t)b*64*HW_;
        for (int j = tid; j < 4096; j += 256){
            const int c = j >> 6, px = j & 63;
            tile[c][px] = xb[(size_t)c*HW_ + h*W_ + w0 + px];
        }
        __syncthreads();
        __hip_bfloat16* ob = xTp + (size_t)b*XPLANE_;
        for (int j = tid; j < 512; j += 256){
            const int px = j >> 3, cs = j & 7;
            union { bf16x8 v; __hip_bfloat16 h8[8]; } R;
#pragma unroll
            for (int q=0;q<8;q++) R.h8[q] = __float2bfloat16(tile[cs*8+q][px]);
            *(bf16x8*)&ob[((size_t)(h+1)*WP_ + (w0+px+1))*64 + cs*8] = R.v;
        }
    }
}

// ---------------------------------------------------------------------------
// Implicit-GEMM 3x3 conv via MFMA, wide: 512 threads, 128-px full row/block.
// ---------------------------------------------------------------------------
template<int G>
__global__ __launch_bounds__(512)
void conv_mfma_k(const __hip_bfloat16* __restrict__ xT,
                 const __hip_bfloat16* __restrict__ wT, int o_total,
                 __hip_bfloat16* __restrict__ outp)   // NHWC padded + ReLU
{
    __shared__ __hip_bfloat16 wA[G*16][64];
    const int tid = threadIdx.x, lane = tid & 63, wid = tid >> 6;
    const int l15 = lane & 15, khi = lane >> 4;
    const int oh = blockIdx.x;
    const int b = blockIdx.z;
    const int px = wid*16 + l15;
    const __hip_bfloat16* xb = xT + (size_t)b*XPLANE_;

    f32x4 acc[G];
    const f32x4 vz = {0.f,0.f,0.f,0.f};
#pragma unroll
    for (int g=0; g<G; ++g) acc[g] = vz;

    for (int k=0; k<9; ++k){
        const int dy = k/3 - 1, dxk = k%3 - 1;
        __syncthreads();
        if (tid < G*16*8){
            const int o = tid >> 3, cs = tid & 7;
            *(bf16x8*)&wA[o][((cs ^ (o&7))*8)] =
                *(const bf16x8*)&wT[((size_t)k*o_total + o)*64 + cs*8];
        }
        __syncthreads();
        const int base = (((oh+1+dy)*WP_) + (px+1+dxk))*64;
#pragma unroll
        for (int s=0; s<2; ++s){
            const bf16x8 bfr = *(const bf16x8*)&xb[base + s*32 + khi*8];
            const int c8 = ((s*4 + khi) ^ (l15 & 7))*8;
#pragma unroll
            for (int g=0; g<G; ++g){
                const bf16x8 afr = *(const bf16x8*)&wA[g*16 + l15][c8];
                acc[g] = __builtin_amdgcn_mfma_f32_16x16x32_bf16(afr, bfr, acc[g], 0,0,0);
            }
        }
    }
    __hip_bfloat16* ob = outp + (size_t)b*XPLANE_;
    const size_t orow = ((size_t)(oh+1)*WP_ + (px+1))*64;
#pragma unroll
    for (int g=0; g<G; ++g){
        union { short4 s4; __hip_bfloat16 h[4]; } o4;
#pragma unroll
        for (int r=0;r<4;r++) o4.h[r] = __float2bfloat16(fmaxf(acc[g][r], 0.f));
        *(short4*)&ob[orow + g*16 + khi*4] = o4.s4;
    }
}

// ---------------------------------------------------------------------------
// MERGED K3: z<8 -> offs conv (m2 -> offsb bf16 NCHW, 36 ch);
//            z>=8 -> att conv (x -> attn bf16 NHWC-128).
// ---------------------------------------------------------------------------
__global__ __launch_bounds__(512)
void conv3_att_k(const __hip_bfloat16* __restrict__ m2T,
                 const __hip_bfloat16* __restrict__ xT,
                 const __hip_bfloat16* __restrict__ wT3,   // [9][48][64]
                 const __hip_bfloat16* __restrict__ wTa,   // [9][128][64]
                 __hip_bfloat16* __restrict__ offsb,       // [b][36][128][128]
                 __hip_bfloat16* __restrict__ attn)        // [b][h][w][128]
{
    __shared__ __hip_bfloat16 wA[64][64];
    const int tid = threadIdx.x, lane = tid & 63, wid = tid >> 6;
    const int l15 = lane & 15, khi = lane >> 4;
    const int oh = blockIdx.x;
    const int px = wid*16 + l15;
    const f32x4 vz = {0.f,0.f,0.f,0.f};

    if (blockIdx.z < 8){
        const int b = blockIdx.z;
        const __hip_bfloat16* xb = m2T + (size_t)b*XPLANE_;
        f32x4 acc[3];
#pragma unroll
        for (int g=0; g<3; ++g) acc[g] = vz;
        for (int k=0; k<9; ++k){
            const int dy = k/3 - 1, dxk = k%3 - 1;
            __syncthreads();
            if (tid < 384){
                const int o = tid >> 3, cs = tid & 7;
                *(bf16x8*)&wA[o][((cs ^ (o&7))*8)] =
                    *(const bf16x8*)&wT3[((size_t)k*48 + o)*64 + cs*8];
            }
            __syncthreads();
            const int base = (((oh+1+dy)*WP_) + (px+1+dxk))*64;
#pragma unroll
            for (int s=0; s<2; ++s){
                const bf16x8 bfr = *(const bf16x8*)&xb[base + s*32 + khi*8];
                const int c8 = ((s*4 + khi) ^ (l15 & 7))*8;
#pragma unroll
                for (int g=0; g<3; ++g){
                    const bf16x8 afr = *(const bf16x8*)&wA[g*16 + l15][c8];
                    acc[g] = __builtin_amdgcn_mfma_f32_16x16x32_bf16(afr, bfr, acc[g], 0,0,0);
                }
            }
        }
#pragma unroll
        for (int g=0; g<3; ++g)
#pragma unroll
            for (int r=0;r<4;r++){
                const int co = g*16 + khi*4 + r;
                if (co < 36)
                    offsb[(((size_t)b*36 + co)*H_ + oh)*W_ + px] =
                        __float2bfloat16(acc[g][r]);
            }
    } else {
        const int zz = blockIdx.z - 8, b = zz & 7, dkb = zz >> 3;
        const __hip_bfloat16* xb = xT + (size_t)b*XPLANE_;
        f32x4 acc[4];
#pragma unroll
        for (int g=0; g<4; ++g) acc[g] = vz;
        for (int k=0; k<9; ++k){
            const int dy = k/3 - 1, dxk = k%3 - 1;
            __syncthreads();
            {
                const int o = tid >> 3, cs = tid & 7;
                *(bf16x8*)&wA[o][((cs ^ (o&7))*8)] =
                    *(const bf16x8*)&wTa[((size_t)k*128 + dkb*64 + o)*64 + cs*8];
            }
            __syncthreads();
            const int base = (((oh+1+dy)*WP_) + (px+1+dxk))*64;
#pragma unroll
            for (int s=0; s<2; ++s){
                const bf16x8 bfr = *(const bf16x8*)&xb[base + s*32 + khi*8];
                const int c8 = ((s*4 + khi) ^ (l15 & 7))*8;
#pragma unroll
                for (int g=0; g<4; ++g){
                    const bf16x8 afr = *(const bf16x8*)&wA[g*16 + l15][c8];
                    acc[g] = __builtin_amdgcn_mfma_f32_16x16x32_bf16(afr, bfr, acc[g], 0,0,0);
                }
            }
        }
        __hip_bfloat16* ab = attn + ((size_t)b*HW_ + (size_t)oh*W_ + px)*128 + dkb*64;
#pragma unroll
        for (int g=0; g<4; ++g){
            union { short4 s4; __hip_bfloat16 h[4]; } o4;
#pragma unroll
            for (int r=0;r<4;r++) o4.h[r] = __float2bfloat16(acc[g][r]);
            *(short4*)&ab[g*16 + khi*4] = o4.s4;
        }
    }
}

// ---------------------------------------------------------------------------
// 4-corner bilinear blend of 8 consecutive channels (NHWC bf16) -> bf16x8.
// ---------------------------------------------------------------------------
__device__ __forceinline__ bf16x8 blend4(const __hip_bfloat16* __restrict__ xb,
                                         int a00, int dxo, int dro, float4 w)
{
    const u32x4 q00 = *(const u32x4*)(xb + a00);
    const u32x4 q01 = *(const u32x4*)(xb + a00 + dxo);
    const u32x4 q10 = *(const u32x4*)(xb + a00 + dro);
    const u32x4 q11 = *(const u32x4*)(xb + a00 + dro + dxo);
    union { bf16x8 v; __hip_bfloat16 h[8]; } R;
#pragma unroll
    for (int p=0;p<4;++p){
        const float l00 = __uint_as_float(q00[p]<<16), h00 = __uint_as_float(q00[p]&0xFFFF0000u);
        const float l01 = __uint_as_float(q01[p]<<16), h01 = __uint_as_float(q01[p]&0xFFFF0000u);
        const float l10 = __uint_as_float(q10[p]<<16), h10 = __uint_as_float(q10[p]&0xFFFF0000u);
        const float l11 = __uint_as_float(q11[p]<<16), h11 = __uint_as_float(q11[p]&0xFFFF0000u);
        R.h[2*p  ] = __float2bfloat16(w.x*l00 + w.y*l01 + w.z*l10 + w.w*l11);
        R.h[2*p+1] = __float2bfloat16(w.x*h00 + w.y*h01 + w.z*h10 + w.w*h11);
    }
    return R.v;
}

// ---------------------------------------------------------------------------
// Fused deformable conv (MFMA) + softmax attention, v8 "octet gather":
// per corner, one wave-instr reads 8 px x FULL 128B channel line (aligned)
// instead of 16 px x 64B half-lines -> line-touches per tap halved (2x).
// Blend in-register, then wave-private XOR-swizzled LDS samp tile rearranges
// to the MFMA B-fragment layout (no barriers: same-wave ds_write->ds_read).
// Meta (corner addr + weights) in LDS per dk. Weights: R7-proven dbuf wA
// with register prefetch + late ds_write, 1 barrier/tap.
// ---------------------------------------------------------------------------
__global__ __launch_bounds__(256)
void deform_att_k(const __hip_bfloat16* __restrict__ xT,
                  const __hip_bfloat16* __restrict__ offsb,
                  const __hip_bfloat16* __restrict__ attn,
                  const __hip_bfloat16* __restrict__ wTd,   // [9][128][64]
                  float* __restrict__ out)
{
    __shared__ __hip_bfloat16 wA[2][64][64];        // 16 KB  [buf][co][c] swz
    __shared__ int4   mI[9][64];                    //  9 KB  (a00,dxo,dro,-)
    __shared__ float4 mW[9][64];                    //  9 KB  (w00,w01,w10,w11)
    __shared__ __hip_bfloat16 samp[4][16][64];      //  8 KB  [wave][px16][ch] swz
    const int tid = threadIdx.x, lane = tid & 63, wid = tid >> 6;
    const int l15 = lane & 15, khi = lane >> 4;
    const int lp  = lane >> 3, lc = lane & 7;       // octet px / ch-chunk
    const int ow0 = blockIdx.x*64, oh = blockIdx.y, b = blockIdx.z;
    const int px = wid*16 + l15;
    const __hip_bfloat16* xb = xT + (size_t)b*XPLANE_;
    const int srow = tid >> 3, scs = tid & 7;
    const int swz = (scs ^ (srow & 7)) * 8;

    f32x4 acc[2][4];
    const f32x4 vz = {0.f,0.f,0.f,0.f};
#pragma unroll
    for (int d=0; d<2; ++d)
#pragma unroll
        for (int g=0; g<4; ++g) acc[d][g] = vz;

    // ---- prologue: stage tap (dk0,k0) weights into wA[0] ----
    {
        const __hip_bfloat16* ws0 = &wTd[(size_t)srow*64 + scs*8];
        *(bf16x8*)&wA[0][srow   ][swz] = *(const bf16x8*)ws0;
        *(bf16x8*)&wA[0][srow+32][swz] = *(const bf16x8*)(ws0 + 32*64);
    }

#pragma unroll
    for (int dk=0; dk<2; ++dk){
        // ---- stage bilinear meta for this dk (9 taps x 64 px) ----
        for (int e=tid; e<576; e+=256){
            const int k = e >> 6, p = e & 63;
            const float oy = __bfloat162float(
                offsb[(((size_t)b*36 + dk*18 + 2*k  )*H_ + oh)*W_ + ow0 + p]);
            const float ox = __bfloat162float(
                offsb[(((size_t)b*36 + dk*18 + 2*k+1)*H_ + oh)*W_ + ow0 + p]);
            const float py  = (float)(oh  - 1 + (k/3))      + oy;
            const float pxx = (float)(ow0 + p - 1 + (k%3))  + ox;
            const float y0f = floorf(py), x0f = floorf(pxx);
            const float ay = py - y0f, ax = pxx - x0f;
            const int y0 = (int)y0f, x0 = (int)x0f;
            const int y1 = y0 + 1,   x1 = x0 + 1;
            const float my0 = (y0 >= 0 && y0 < H_) ? 1.f : 0.f;
            const float my1 = (y1 >= 0 && y1 < H_) ? 1.f : 0.f;
            const float mx0 = (x0 >= 0 && x0 < W_) ? 1.f : 0.f;
            const float mx1 = (x1 >= 0 && x1 < W_) ? 1.f : 0.f;
            const int y0c = min(max(y0,0),H_-1), y1c = min(max(y1,0),H_-1);
            const int x0c = min(max(x0,0),W_-1), x1c = min(max(x1,0),W_-1);
            const float wy0 = my0*(1.f-ay), wy1 = my1*ay;
            const float wx0 = mx0*(1.f-ax), wx1 = mx1*ax;
            mI[k][p] = make_int4(((y0c+1)*WP_ + (x0c+1))*64,
                                 (x1c-x0c)*64, (y1c-y0c)*WP_*64, 0);
            mW[k][p] = make_float4(wy0*wx0, wy0*wx1, wy1*wx0, wy1*wx1);
        }
        __syncthreads();   // meta visible; prologue/prefetched wA visible

        for (int k=0; k<9; ++k){
            const int t = dk*9 + k;
            // ---- prefetch next tap's weights into registers ----
            bf16x8 nw0 = {}, nw1 = {};
            const bool hn = (t < 17);
            const int ndk = (k==8) ? dk+1 : dk;
            const int nk  = (k==8) ? 0 : k+1;
            if (hn){
                const __hip_bfloat16* ws0 =
                    &wTd[((size_t)nk*128 + ndk*64 + srow)*64 + scs*8];
                nw0 = *(const bf16x8*)ws0;
                nw1 = *(const bf16x8*)(ws0 + 32*64);
            }
            // ---- octet gathers: 2 octets x 4 corners, 8 px x 128B each ----
#pragma unroll
            for (int oct=0; oct<2; ++oct){
                const int pxo = wid*16 + oct*8 + lp;
                const int4   mi = mI[k][pxo];    // broadcast among 8 lanes
                const float4 mw = mW[k][pxo];
                const bf16x8 v = blend4(xb, mi.x + lc*8, mi.y, mi.z, mw);
                const int row = oct*8 + lp;
                *(bf16x8*)&samp[wid][row][((lc ^ (row & 7))*8)] = v;
            }
            // ---- fragment reads (wave-private, no barrier) + MFMA ----
            const __hip_bfloat16 (*wr)[64] = (const __hip_bfloat16 (*)[64])wA[t & 1];
#pragma unroll
            for (int s=0; s<2; ++s){
                const int c8 = ((s*4 + khi) ^ (l15 & 7))*8;
                const bf16x8 bfr = *(const bf16x8*)&samp[wid][l15][c8];
#pragma unroll
                for (int g=0; g<4; ++g){
                    const bf16x8 afr = *(const bf16x8*)&wr[g*16 + l15][c8];
                    acc[dk][g] = __builtin_amdgcn_mfma_f32_16x16x32_bf16(afr, bfr, acc[dk][g], 0,0,0);
                }
            }
            // ---- late ds_write of prefetched weights ----
            if (hn){
                *(bf16x8*)&wA[(t+1)&1][srow   ][swz] = nw0;
                *(bf16x8*)&wA[(t+1)&1][srow+32][swz] = nw1;
            }
            __syncthreads();   // wA[t&1] reads done; wA[(t+1)&1] visible
        }
    }
    // ---- epilogue: NHWC-128 att reads + softmax + write ----
    const __hip_bfloat16* ab = attn + ((size_t)b*HW_ + (size_t)oh*W_ + ow0 + px)*128;
#pragma unroll
    for (int g=0; g<4; ++g){
        union { short4 s4; __hip_bfloat16 h[4]; } a0v, a1v;
        a0v.s4 = *(const short4*)&ab[     g*16 + khi*4];
        a1v.s4 = *(const short4*)&ab[64 + g*16 + khi*4];
#pragma unroll
        for (int r=0; r<4; ++r){
            const int co = g*16 + khi*4 + r;
            const float a0 = __bfloat162float(a0v.h[r]);
            const float a1 = __bfloat162float(a1v.h[r]);
            const float f0 = 1.f / (1.f + __expf(a1 - a0));
            out[(((size_t)b*64 + co)*H_ + oh)*W_ + ow0 + px] =
                acc[0][g][r]*f0 + acc[1][g][r]*(1.f - f0);
        }
    }
}

// ---------------------------------------------------------------------------
extern "C" void kernel_launch(void* const* d_in, const int* in_sizes, int n_in,
                              void* d_out, int out_size, void* d_ws, size_t ws_size,
                              hipStream_t stream)
{
    const float* x  = (const float*)d_in[0];
    const float* w1 = (const float*)d_in[1];
    const float* w2 = (const float*)d_in[2];
    const float* w3 = (const float*)d_in[3];
    const float* wa = (const float*)d_in[4];
    const float* wd = (const float*)d_in[5];
    float* out = (float*)d_out;

    // ---- workspace layout (halfword units), total ~78.1 MB ----
    __hip_bfloat16* xTp   = (__hip_bfloat16*)d_ws;       // 8,652,800
    __hip_bfloat16* m2Tp  = xTp   + (size_t)8652800;     // 8,652,800
    __hip_bfloat16* wT1   = m2Tp  + (size_t)8652800;     // 36864
    __hip_bfloat16* wT2   = wT1   + 36864;               // 36864
    __hip_bfloat16* wT3   = wT2   + 36864;               // 27648
    __hip_bfloat16* wTa   = wT3   + 27648;               // 73728
    __hip_bfloat16* wTd   = wTa   + 73728;               // 73728
    __hip_bfloat16* offsb = wTd   + 73728;               // 4,718,592 (bf16 NCHW)
    __hip_bfloat16* m1Tp  = offsb + (size_t)4718592;     // 8,652,800
    __hip_bfloat16* attn  = m1Tp;                        // 16,777,216 (m1 dead + tail)

    const dim3 blk(256), blkw(512);
    prep_k<<<dim3(3018), blk, 0, stream>>>(x, w1,w2,w3,wa,wd,
                                           xTp, m1Tp, m2Tp,
                                           wT1, wT2, wT3, wTa, wTd);
    conv_mfma_k<4><<<dim3(128,1,8), blkw, 0, stream>>>(xTp,  wT1, 64, m1Tp);
    conv_mfma_k<4><<<dim3(128,1,8), blkw, 0, stream>>>(m1Tp, wT2, 64, m2Tp);
    conv3_att_k<<<dim3(128,1,24), blkw, 0, stream>>>(m2Tp, xTp, wT3, wTa,
                                                     offsb, attn);
    // fused deformable conv + attention (v8: octet full-line gathers)
    deform_att_k<<<dim3(2,128,8), blk, 0, stream>>>(xTp, offsb, attn, wTd, out);
}